// Round 1
// baseline (726.519 us; speedup 1.0000x reference)
//
#include <hip/hip_runtime.h>
#include <hip/hip_bf16.h>
#include <math.h>

// Problem constants
#define Bq 64
#define Tt 2048
#define TQn 2
#define HIDn 1024
#define ENCn 512
#define Un 256
#define FILTn 32
#define KKn 31

// Main-pass tiling
#define TTILE 32
#define NCHUNK (Tt / TTILE)     // 64
#define NCPB 4                  // chunks per block (persistent-ish blocks)
#define LDK 520                 // padded LDS row (bf16): 512+8, 16B-aligned rows

typedef short short8 __attribute__((ext_vector_type(8)));
typedef float f32x4  __attribute__((ext_vector_type(4)));
typedef unsigned short ushort_t;
typedef unsigned int   uint_t;

union S8 { short8 v; uint_t u[4]; };

__device__ __forceinline__ ushort_t f2b(float f) {          // RNE scalar (prep only)
    union { float f; uint_t u; } x; x.f = f;
    uint_t r = x.u + 0x7fffu + ((x.u >> 16) & 1u);
    return (ushort_t)(r >> 16);
}
__device__ __forceinline__ uint_t cvt_pk(float lo, float hi) {  // HW v_cvt_pk_bf16_f32
    union { __hip_bfloat162 h; uint_t u; } x;
    x.h = __float22bfloat162_rn(make_float2(lo, hi));
    return x.u;
}
__device__ __forceinline__ float b2f(uint_t u16) {
    union { uint_t i; float f; } x; x.i = u16 << 16;
    return x.f;
}
__device__ __forceinline__ float tanh_fast(float x) {
    const float e = __expf(2.0f * x);
    return 1.0f - 2.0f * __builtin_amdgcn_rcpf(e + 1.0f);
}

// B-layout helper: element (v, k) of WmWe^T goes to the slot wave-load order expects:
// seg = (k>>5)*16 + (v>>6)*4 + ((v>>4)&3), lane = ((k>>3)&3)*16 + (v&15), j = k&7
// ushort idx = seg*512 + lane*8 + j   -> every wave B-load is one contiguous 1KB txn.
__device__ __forceinline__ int bp_idx(int v, int k) {
    const int seg = (k >> 5) * 16 + (v >> 6) * 4 + ((v >> 4) & 3);
    const int ln  = ((k >> 3) & 3) * 16 + (v & 15);
    return seg * 512 + ln * 8 + (k & 7);
}

// ---------------- prep1: Bp (permuted WmWeT), CWT (permuted), cvec ----------------
__global__ void k_prep1(const float* __restrict__ We, const float* __restrict__ Wm,
                        const float* __restrict__ Wl, const float* __restrict__ conv_w,
                        const float* __restrict__ bq, const float* __restrict__ bm,
                        const float* __restrict__ bl, const float* __restrict__ conv_b,
                        ushort_t* __restrict__ Bp, ushort_t* __restrict__ CWT,
                        float* __restrict__ cvec)
{
    const int blk = blockIdx.x;
    const int v = threadIdx.x;
    if (blk < 512) {               // Bp slot for (v, k=e) = bf16(sum_u Wm[e,u] We[u,v])
        const int e = blk;
        float a0 = 0.f, a1 = 0.f, a2 = 0.f, a3 = 0.f;
        #pragma unroll 4
        for (int u = 0; u < Un; u += 4) {
            a0 += Wm[(size_t)e * Un + u + 0] * We[(u + 0) * Un + v];
            a1 += Wm[(size_t)e * Un + u + 1] * We[(u + 1) * Un + v];
            a2 += Wm[(size_t)e * Un + u + 2] * We[(u + 2) * Un + v];
            a3 += Wm[(size_t)e * Un + u + 3] * We[(u + 3) * Un + v];
        }
        Bp[bp_idx(v, e)] = f2b((a0 + a1) + (a2 + a3));
    } else if (blk < 516) {        // CWT (permuted, k<32 so seg uses s=0) for a 64-wide v chunk
        const int vc = (blk - 512) * 64;
        __shared__ float wlwe[FILTn * 64];
        for (int i = threadIdx.x; i < FILTn * 64; i += 256) {
            const int f = i >> 6, vv = i & 63;
            float a = 0.f;
            #pragma unroll 8
            for (int u = 0; u < Un; ++u) a += Wl[f * Un + u] * We[u * Un + vc + vv];
            wlwe[f * 64 + vv] = a;
        }
        __syncthreads();
        for (int i = threadIdx.x; i < 64 * 32; i += 256) {
            const int vv = i >> 5, k = i & 31;
            float a = 0.f;
            if (k < KKn) {
                #pragma unroll
                for (int f = 0; f < FILTn; ++f) a += conv_w[f * KKn + k] * wlwe[f * 64 + vv];
            }
            CWT[bp_idx(vc + vv, k)] = f2b(a);   // k<32 -> same formula, s=0
        }
    } else {                       // cvec[u] = bq+bm+bl+conv_b@Wl
        const int u = v;
        float a = bq[u] + bm[u] + bl[u];
        #pragma unroll
        for (int f = 0; f < FILTn; ++f) a += conv_b[f] * Wl[f * Un + u];
        cvec[u] = a;
    }
}

// ---------------- k_g: g[b,u] = q1@Wq (+cvec at y==0). grid (64,8), atomic ----------------
__global__ void k_g(const float* __restrict__ query, const float* __restrict__ Wq,
                    const float* __restrict__ cvec, float* __restrict__ g)
{
    const int b = blockIdx.x, hs = blockIdx.y * 128, u = threadIdx.x;
    const float* q = query + ((size_t)b * TQn + 1) * HIDn + hs;
    float a0 = 0.f, a1 = 0.f, a2 = 0.f, a3 = 0.f;
    #pragma unroll 4
    for (int h = 0; h < 128; h += 4) {
        a0 += q[h + 0] * Wq[(size_t)(hs + h + 0) * Un + u];
        a1 += q[h + 1] * Wq[(size_t)(hs + h + 1) * Un + u];
        a2 += q[h + 2] * Wq[(size_t)(hs + h + 2) * Un + u];
        a3 += q[h + 3] * Wq[(size_t)(hs + h + 3) * Un + u];
    }
    float acc = (a0 + a1) + (a2 + a3);
    if (blockIdx.y == 0) acc += cvec[u];
    atomicAdd(&g[b * Un + u], acc);
}

// ---------------- k_zconst: zconst[b,v] = g@We (+be at y==0). grid (64,4), atomic ----------------
__global__ void k_zconst(const float* __restrict__ g, const float* __restrict__ We,
                         const float* __restrict__ be, float* __restrict__ zconst)
{
    const int b = blockIdx.x, us = blockIdx.y * 64, v = threadIdx.x;
    float a0 = 0.f, a1 = 0.f;
    #pragma unroll 4
    for (int u = us; u < us + 64; u += 2) {
        a0 += g[b * Un + u]     * We[(size_t)u * Un + v];
        a1 += g[b * Un + u + 1] * We[(size_t)(u + 1) * Un + v];
    }
    float acc = a0 + a1;
    if (blockIdx.y == 0) acc += be[v];
    atomicAdd(&zconst[b * Un + v], acc);
}

// ---------------- main fused MFMA pass ----------------
// Persistent-ish blocks: grid (64 b x 16 cgroups), each block runs NCPB=4 consecutive
// 32-row t-chunks. T14 staging: next chunk's tile is loaded to registers during the
// current chunk's MFMA+epilogue; only cvt+ds_write is serial. B table (Bp) is laid out
// so each wave B-load is one contiguous 1KB transaction. zA/zS/zSsum/zStsum partials
// accumulate in registers across chunks -> one atomic set per block.
__global__ __launch_bounds__(256, 3) void attn_main(
    const float* __restrict__ memory, const float* __restrict__ state,
    const ushort_t* __restrict__ Bp, const ushort_t* __restrict__ CWT,
    const float* __restrict__ zconst, const float* __restrict__ v_a,
    float* __restrict__ zA, float* __restrict__ zS,
    float* __restrict__ zSsum, float* __restrict__ zStsum)
{
    const int blk = blockIdx.x;
    const int b  = blk >> 4;            // 16 cgroups per b
    const int cg = blk & 15;
    const int tid = threadIdx.x;

    __shared__ __align__(16) ushort_t mem_s[TTILE * LDK];   // 33280 B
    __shared__ __align__(16) float sw_raw[80];
    __shared__ __align__(16) float ep_s[4][TTILE];
    __shared__ __align__(16) float s_s[TTILE];
    float* sw = sw_raw + 1;   // sw[i] = state[t0-15+i], i in [0,63)

    const int lane = tid & 63;
    const int w    = tid >> 6;
    const int lm   = lane & 15;
    const int lq   = lane >> 4;
    const int ncol0 = w * 64 + lm;

    // Permuted-B pointers: contiguous 1KB per wave-load. Per step s add s*8192 ushorts.
    const ushort_t* bp0 = Bp + (size_t)((w * 4 + 0) * 512 + lane * 8);
    const ushort_t* bp1 = bp0 + 512;
    const ushort_t* bp2 = bp0 + 1024;
    const ushort_t* bp3 = bp0 + 1536;
    const ushort_t* cp0 = CWT + (size_t)((w * 4 + 0) * 512 + lane * 8);

    // hoisted epilogue constants
    float zc[4], va[4];
    #pragma unroll
    for (int nbi = 0; nbi < 4; ++nbi) {
        const int col = ncol0 + nbi * 16;
        zc[nbi] = zconst[b * Un + col];
        va[nbi] = v_a[col];
    }

    // cross-chunk register accumulators
    const int e0 = tid << 1;
    float aA0 = 0.f, aA1 = 0.f, aS0 = 0.f, aS1 = 0.f;
    float ssum_acc = 0.f, stsum_acc = 0.f;

    // ---- prologue: prefetch chunk 0 tile + state window into registers ----
    float4 pf[16];
    float  swv = 0.f;
    {
        const int t0 = (cg * NCPB) * TTILE;
        const float4* memv4 = (const float4*)(memory + ((size_t)b * Tt + t0) * ENCn);
        #pragma unroll
        for (int i = 0; i < 8; ++i) {
            const int idx = i * 256 + tid;
            pf[2 * i]     = memv4[2 * idx];
            pf[2 * i + 1] = memv4[2 * idx + 1];
        }
        const int t = t0 - 15 + tid;
        if (tid < 63 && t >= 0 && t < Tt) swv = state[b * Tt + t];
    }

    #pragma unroll 1
    for (int cc = 0; cc < NCPB; ++cc) {
        const int t0 = (cg * NCPB + cc) * TTILE;

        if (cc) __syncthreads();             // B1: LDS free of prev-chunk readers

        // ---- write phase: registers -> LDS (bf16) ----
        if (tid < 63) sw[tid] = swv;
        #pragma unroll
        for (int i = 0; i < 8; ++i) {
            const int idx = i * 256 + tid;
            const int row = idx >> 6;
            const int cw8 = (idx & 63) << 3;
            S8 v;
            v.u[0] = cvt_pk(pf[2 * i].x,     pf[2 * i].y);
            v.u[1] = cvt_pk(pf[2 * i].z,     pf[2 * i].w);
            v.u[2] = cvt_pk(pf[2 * i + 1].x, pf[2 * i + 1].y);
            v.u[3] = cvt_pk(pf[2 * i + 1].z, pf[2 * i + 1].w);
            *(short8*)&mem_s[row * LDK + cw8] = v.v;
        }
        __syncthreads();                     // B2: tile ready

        // ---- issue B prefetch (oldest, needed first) ----
        short8 bbuf[2][4];
        bbuf[0][0] = *(const short8*)(bp0);
        bbuf[0][1] = *(const short8*)(bp1);
        bbuf[0][2] = *(const short8*)(bp2);
        bbuf[0][3] = *(const short8*)(bp3);
        bbuf[1][0] = *(const short8*)(bp0 + 8192);
        bbuf[1][1] = *(const short8*)(bp1 + 8192);
        bbuf[1][2] = *(const short8*)(bp2 + 8192);
        bbuf[1][3] = *(const short8*)(bp3 + 8192);

        // ---- issue next chunk's tile loads (hidden under MFMA + epilogue) ----
        if (cc < NCPB - 1) {
            const float4* memn = (const float4*)(memory + ((size_t)b * Tt + t0 + TTILE) * ENCn);
            #pragma unroll
            for (int i = 0; i < 8; ++i) {
                const int idx = i * 256 + tid;
                pf[2 * i]     = memn[2 * idx];
                pf[2 * i + 1] = memn[2 * idx + 1];
            }
            swv = 0.f;
            const int t = t0 + TTILE - 15 + tid;
            if (tid < 63 && t < Tt) swv = state[b * Tt + t];   // t>=0 guaranteed here
        }

        // ---- MFMA main loop over K=512 (16 steps of K=32) ----
        f32x4 acc[2][4] = {};
        const ushort_t* arow0 = &mem_s[(lm) * LDK + lq * 8];
        const ushort_t* arow1 = &mem_s[(16 + lm) * LDK + lq * 8];
        short8 a0c = *(const short8*)(arow0);
        short8 a1c = *(const short8*)(arow1);

        #pragma unroll
        for (int s = 0; s < 16; ++s) {
            const int sa = ((s + 1) & 15) * 32;
            const short8 a0n = *(const short8*)(arow0 + sa);
            const short8 a1n = *(const short8*)(arow1 + sa);
            acc[0][0] = __builtin_amdgcn_mfma_f32_16x16x32_bf16(a0c, bbuf[s & 1][0], acc[0][0], 0, 0, 0);
            acc[0][1] = __builtin_amdgcn_mfma_f32_16x16x32_bf16(a0c, bbuf[s & 1][1], acc[0][1], 0, 0, 0);
            acc[0][2] = __builtin_amdgcn_mfma_f32_16x16x32_bf16(a0c, bbuf[s & 1][2], acc[0][2], 0, 0, 0);
            acc[0][3] = __builtin_amdgcn_mfma_f32_16x16x32_bf16(a0c, bbuf[s & 1][3], acc[0][3], 0, 0, 0);
            acc[1][0] = __builtin_amdgcn_mfma_f32_16x16x32_bf16(a1c, bbuf[s & 1][0], acc[1][0], 0, 0, 0);
            acc[1][1] = __builtin_amdgcn_mfma_f32_16x16x32_bf16(a1c, bbuf[s & 1][1], acc[1][1], 0, 0, 0);
            acc[1][2] = __builtin_amdgcn_mfma_f32_16x16x32_bf16(a1c, bbuf[s & 1][2], acc[1][2], 0, 0, 0);
            acc[1][3] = __builtin_amdgcn_mfma_f32_16x16x32_bf16(a1c, bbuf[s & 1][3], acc[1][3], 0, 0, 0);
            const int sn = ((s + 2) & 15) * 8192;
            bbuf[s & 1][0] = *(const short8*)(bp0 + sn);
            bbuf[s & 1][1] = *(const short8*)(bp1 + sn);
            bbuf[s & 1][2] = *(const short8*)(bp2 + sn);
            bbuf[s & 1][3] = *(const short8*)(bp3 + sn);
            a0c = a0n; a1c = a1n;
        }

        // conv as one extra K=32 MFMA step: A[t][k] = sw[t + k], B = CWT (permuted)
        {
            S8 ca0, ca1;
            #pragma unroll
            for (int j = 0; j < 4; ++j) {
                const int base0 = lm + lq * 8 + 2 * j;
                ca0.u[j] = cvt_pk(sw[base0],      sw[base0 + 1]);
                ca1.u[j] = cvt_pk(sw[base0 + 16], sw[base0 + 17]);
            }
            const short8 cb0 = *(const short8*)(cp0);
            const short8 cb1 = *(const short8*)(cp0 + 512);
            const short8 cb2 = *(const short8*)(cp0 + 1024);
            const short8 cb3 = *(const short8*)(cp0 + 1536);
            acc[0][0] = __builtin_amdgcn_mfma_f32_16x16x32_bf16(ca0.v, cb0, acc[0][0], 0, 0, 0);
            acc[0][1] = __builtin_amdgcn_mfma_f32_16x16x32_bf16(ca0.v, cb1, acc[0][1], 0, 0, 0);
            acc[0][2] = __builtin_amdgcn_mfma_f32_16x16x32_bf16(ca0.v, cb2, acc[0][2], 0, 0, 0);
            acc[0][3] = __builtin_amdgcn_mfma_f32_16x16x32_bf16(ca0.v, cb3, acc[0][3], 0, 0, 0);
            acc[1][0] = __builtin_amdgcn_mfma_f32_16x16x32_bf16(ca1.v, cb0, acc[1][0], 0, 0, 0);
            acc[1][1] = __builtin_amdgcn_mfma_f32_16x16x32_bf16(ca1.v, cb1, acc[1][1], 0, 0, 0);
            acc[1][2] = __builtin_amdgcn_mfma_f32_16x16x32_bf16(ca1.v, cb2, acc[1][2], 0, 0, 0);
            acc[1][3] = __builtin_amdgcn_mfma_f32_16x16x32_bf16(ca1.v, cb3, acc[1][3], 0, 0, 0);
        }

        // ---- epilogue: zconst + tanh + v_a dot; reduce over the 16 n-lanes ----
        #pragma unroll
        for (int mb = 0; mb < 2; ++mb) {
            #pragma unroll
            for (int r = 0; r < 4; ++r) {
                float ep = 0.f;
                #pragma unroll
                for (int nbi = 0; nbi < 4; ++nbi)
                    ep += tanh_fast(acc[mb][nbi][r] + zc[nbi]) * va[nbi];
                ep += __shfl_xor(ep, 1, 64);
                ep += __shfl_xor(ep, 2, 64);
                ep += __shfl_xor(ep, 4, 64);
                ep += __shfl_xor(ep, 8, 64);
                if (lm == 0) ep_s[w][mb * 16 + lq * 4 + r] = ep;   // C/D: row = quad*4+reg
            }
        }
        __syncthreads();                     // E1

        if (tid < 64) {
            float s = 0.f, st = 0.f;
            if (tid < TTILE) {
                const float energy = ep_s[0][tid] + ep_s[1][tid] + ep_s[2][tid] + ep_s[3][tid];
                s = __builtin_amdgcn_rcpf(1.0f + __expf(-energy));
                s_s[tid] = s;
                st = sw[15 + tid];
            }
            float ssum = s, stsum = st;
            #pragma unroll
            for (int off = 32; off >= 1; off >>= 1) {
                ssum  += __shfl_xor(ssum,  off, 64);
                stsum += __shfl_xor(stsum, off, 64);
            }
            ssum_acc  += ssum;
            stsum_acc += stsum;
        }
        __syncthreads();                     // E2: s_s ready

        // A/S weighted accumulation from the LDS bf16 tile; thread owns e = 2*tid, 2*tid+1
        #pragma unroll 2
        for (int r4 = 0; r4 < TTILE / 4; ++r4) {
            const float4 sv4 = *(const float4*)&s_s[r4 * 4];
            const float4 st4 = *(const float4*)&sw[15 + r4 * 4];
            const float sv[4] = {sv4.x, sv4.y, sv4.z, sv4.w};
            const float st[4] = {st4.x, st4.y, st4.z, st4.w};
            #pragma unroll
            for (int j = 0; j < 4; ++j) {
                const int r = r4 * 4 + j;
                const uint_t mm = *(const uint_t*)&mem_s[r * LDK + e0];
                const float m0 = b2f(mm & 0xffffu);
                const float m1 = b2f(mm >> 16);
                aA0 += st[j] * m0; aA1 += st[j] * m1;
                aS0 += sv[j] * m0; aS1 += sv[j] * m1;
            }
        }
    }

    // ---- one atomic set per block ----
    if (tid == 0) {
        atomicAdd(&zSsum[b],  ssum_acc);
        atomicAdd(&zStsum[b], stsum_acc);
    }
    atomicAdd(&zA[b * ENCn + e0],     aA0);
    atomicAdd(&zA[b * ENCn + e0 + 1], aA1);
    atomicAdd(&zS[b * ENCn + e0],     aS0);
    atomicAdd(&zS[b * ENCn + e0 + 1], aS1);
}

// ---------------- finalize ----------------
__global__ void k_final(const float* __restrict__ zA, const float* __restrict__ zS,
                        const float* __restrict__ zSsum, const float* __restrict__ zStsum,
                        const float* __restrict__ Wm, const float* __restrict__ bm,
                        float* __restrict__ out)
{
    const int b = blockIdx.x, e0 = blockIdx.y * 128, u = threadIdx.x;
    const float inv = 1.0f / zSsum[b];
    float a0 = 0.f, a1 = 0.f;
    #pragma unroll 4
    for (int e = e0; e < e0 + 128; e += 2) {
        const float c0 = zA[b * ENCn + e]     + zS[b * ENCn + e]     * inv;
        const float c1 = zA[b * ENCn + e + 1] + zS[b * ENCn + e + 1] * inv;
        a0 += c0 * Wm[(size_t)e * Un + u];
        a1 += c1 * Wm[(size_t)(e + 1) * Un + u];
    }
    float acc = a0 + a1;
    if (blockIdx.y == 0) acc += bm[u] * (zStsum[b] + 1.0f);
    atomicAdd(&out[b * Un + u], acc);
}

// ---------------- launch ----------------
extern "C" void kernel_launch(void* const* d_in, const int* in_sizes, int n_in,
                              void* d_out, int out_size, void* d_ws, size_t ws_size,
                              hipStream_t stream)
{
    const float* query  = (const float*)d_in[0];
    const float* state  = (const float*)d_in[1];
    const float* memory = (const float*)d_in[2];
    const float* Wq     = (const float*)d_in[3];
    const float* bq     = (const float*)d_in[4];
    const float* Wm     = (const float*)d_in[5];
    const float* bm     = (const float*)d_in[6];
    const float* Wl     = (const float*)d_in[7];
    const float* bl     = (const float*)d_in[8];
    const float* conv_w = (const float*)d_in[9];
    const float* conv_b = (const float*)d_in[10];
    const float* We     = (const float*)d_in[11];
    const float* be     = (const float*)d_in[12];
    const float* v_a    = (const float*)d_in[13];
    float* out = (float*)d_out;

    // workspace layout (float offsets) — unchanged from previous version
    float* ws      = (float*)d_ws;
    float* zA      = ws;                   // 32768
    float* zS      = ws + 32768;           // 32768
    float* zSsum   = ws + 65536;           // 64
    float* zStsum  = ws + 65600;           // 64
    float* g_      = ws + 65664;           // 16384 (atomic-accumulated)
    float* zconst  = ws + 82048;           // 16384 (atomic-accumulated) -> zero ends 98432
    float* cvec    = ws + 98432;           // 256
    ushort_t* Bp    = (ushort_t*)(ws + 98688);   // 131072 ushorts (permuted WmWeT)
    ushort_t* CWT   = (ushort_t*)(ws + 164224);  // 8192 ushorts (permuted)

    hipMemsetAsync(ws, 0, 98432 * sizeof(float), stream);
    hipMemsetAsync(out, 0, (size_t)Bq * Un * sizeof(float), stream);

    hipLaunchKernelGGL(k_prep1, dim3(517), dim3(Un), 0, stream,
                       We, Wm, Wl, conv_w, bq, bm, bl, conv_b, Bp, CWT, cvec);
    hipLaunchKernelGGL(k_g, dim3(Bq, 8), dim3(Un), 0, stream, query, Wq, cvec, g_);
    hipLaunchKernelGGL(k_zconst, dim3(Bq, 4), dim3(Un), 0, stream, g_, We, be, zconst);
    hipLaunchKernelGGL(attn_main, dim3(Bq * NCHUNK / NCPB), dim3(256), 0, stream,
                       memory, state, Bp, CWT, zconst, v_a, zA, zS, zSsum, zStsum);
    hipLaunchKernelGGL(k_final, dim3(Bq, 4), dim3(Un), 0, stream,
                       zA, zS, zSsum, zStsum, Wm, bm, out);
}

// Round 3
// 608.409 us; speedup vs baseline: 1.1941x; 1.1941x over previous
//
#include <hip/hip_runtime.h>
#include <hip/hip_bf16.h>
#include <math.h>

// Problem constants
#define Bq 64
#define Tt 2048
#define TQn 2
#define HIDn 1024
#define ENCn 512
#define Un 256
#define FILTn 32
#define KKn 31

// Main-pass tiling
#define TTILE 32
#define NCHUNK (Tt / TTILE)     // 64

typedef short short8 __attribute__((ext_vector_type(8)));
typedef float f32x4  __attribute__((ext_vector_type(4)));
typedef unsigned short ushort_t;
typedef unsigned int   uint_t;

union S8 { short8 v; uint_t u[4]; };

__device__ __forceinline__ ushort_t f2b(float f) {          // RNE scalar (prep only)
    union { float f; uint_t u; } x; x.f = f;
    uint_t r = x.u + 0x7fffu + ((x.u >> 16) & 1u);
    return (ushort_t)(r >> 16);
}
__device__ __forceinline__ uint_t cvt_pk(float lo, float hi) {  // HW v_cvt_pk_bf16_f32
    union { __hip_bfloat162 h; uint_t u; } x;
    x.h = __float22bfloat162_rn(make_float2(lo, hi));
    return x.u;
}
__device__ __forceinline__ float tanh_fast(float x) {
    const float e = __expf(2.0f * x);
    return 1.0f - 2.0f * __builtin_amdgcn_rcpf(e + 1.0f);
}

// B-layout helper: element (v, k) of WmWe^T goes to the slot wave-load order expects:
// seg = (k>>5)*16 + (v>>6)*4 + ((v>>4)&3), lane = ((k>>3)&3)*16 + (v&15), j = k&7
// ushort idx = seg*512 + lane*8 + j   -> every wave B-load is one contiguous 1KB txn.
__device__ __forceinline__ int bp_idx(int v, int k) {
    const int seg = (k >> 5) * 16 + (v >> 6) * 4 + ((v >> 4) & 3);
    const int ln  = ((k >> 3) & 3) * 16 + (v & 15);
    return seg * 512 + ln * 8 + (k & 7);
}

// ---------------- prep1: Bp (permuted WmWeT), CWT (permuted), cvec ----------------
__global__ void k_prep1(const float* __restrict__ We, const float* __restrict__ Wm,
                        const float* __restrict__ Wl, const float* __restrict__ conv_w,
                        const float* __restrict__ bq, const float* __restrict__ bm,
                        const float* __restrict__ bl, const float* __restrict__ conv_b,
                        ushort_t* __restrict__ Bp, ushort_t* __restrict__ CWT,
                        float* __restrict__ cvec)
{
    const int blk = blockIdx.x;
    const int v = threadIdx.x;
    if (blk < 512) {               // Bp slot for (v, k=e) = bf16(sum_u Wm[e,u] We[u,v])
        const int e = blk;
        float a0 = 0.f, a1 = 0.f, a2 = 0.f, a3 = 0.f;
        #pragma unroll 4
        for (int u = 0; u < Un; u += 4) {
            a0 += Wm[(size_t)e * Un + u + 0] * We[(u + 0) * Un + v];
            a1 += Wm[(size_t)e * Un + u + 1] * We[(u + 1) * Un + v];
            a2 += Wm[(size_t)e * Un + u + 2] * We[(u + 2) * Un + v];
            a3 += Wm[(size_t)e * Un + u + 3] * We[(u + 3) * Un + v];
        }
        Bp[bp_idx(v, e)] = f2b((a0 + a1) + (a2 + a3));
    } else if (blk < 516) {        // CWT (permuted, k<32) for a 64-wide v chunk
        const int vc = (blk - 512) * 64;
        __shared__ float wlwe[FILTn * 64];
        for (int i = threadIdx.x; i < FILTn * 64; i += 256) {
            const int f = i >> 6, vv = i & 63;
            float a = 0.f;
            #pragma unroll 8
            for (int u = 0; u < Un; ++u) a += Wl[f * Un + u] * We[u * Un + vc + vv];
            wlwe[f * 64 + vv] = a;
        }
        __syncthreads();
        for (int i = threadIdx.x; i < 64 * 32; i += 256) {
            const int vv = i >> 5, k = i & 31;
            float a = 0.f;
            if (k < KKn) {
                #pragma unroll
                for (int f = 0; f < FILTn; ++f) a += conv_w[f * KKn + k] * wlwe[f * 64 + vv];
            }
            CWT[bp_idx(vc + vv, k)] = f2b(a);
        }
    } else {                       // cvec[u] = bq+bm+bl+conv_b@Wl
        const int u = v;
        float a = bq[u] + bm[u] + bl[u];
        #pragma unroll
        for (int f = 0; f < FILTn; ++f) a += conv_b[f] * Wl[f * Un + u];
        cvec[u] = a;
    }
}

// ---------------- k_g: g[b,u] = q1@Wq (+cvec at y==0). grid (64,8), atomic ----------------
__global__ void k_g(const float* __restrict__ query, const float* __restrict__ Wq,
                    const float* __restrict__ cvec, float* __restrict__ g)
{
    const int b = blockIdx.x, hs = blockIdx.y * 128, u = threadIdx.x;
    const float* q = query + ((size_t)b * TQn + 1) * HIDn + hs;
    float a0 = 0.f, a1 = 0.f, a2 = 0.f, a3 = 0.f;
    #pragma unroll 4
    for (int h = 0; h < 128; h += 4) {
        a0 += q[h + 0] * Wq[(size_t)(hs + h + 0) * Un + u];
        a1 += q[h + 1] * Wq[(size_t)(hs + h + 1) * Un + u];
        a2 += q[h + 2] * Wq[(size_t)(hs + h + 2) * Un + u];
        a3 += q[h + 3] * Wq[(size_t)(hs + h + 3) * Un + u];
    }
    float acc = (a0 + a1) + (a2 + a3);
    if (blockIdx.y == 0) acc += cvec[u];
    atomicAdd(&g[b * Un + u], acc);
}

// ---------------- k_zconst: zconst[b,v] = g@We (+be at y==0). grid (64,4), atomic ----------------
__global__ void k_zconst(const float* __restrict__ g, const float* __restrict__ We,
                         const float* __restrict__ be, float* __restrict__ zconst)
{
    const int b = blockIdx.x, us = blockIdx.y * 64, v = threadIdx.x;
    float a0 = 0.f, a1 = 0.f;
    #pragma unroll 4
    for (int u = us; u < us + 64; u += 2) {
        a0 += g[b * Un + u]     * We[(size_t)u * Un + v];
        a1 += g[b * Un + u + 1] * We[(size_t)(u + 1) * Un + v];
    }
    float acc = a0 + a1;
    if (blockIdx.y == 0) acc += be[v];
    atomicAdd(&zconst[b * Un + v], acc);
}

// ---------------- main fused MFMA pass (no LDS tile, direct-global A) ----------------
// Block = (b, 32-row t-chunk), 256 thr = 4 waves; wave w owns v-cols w*64..w*64+63.
// A fragments are read straight from global fp32 (two float4 per row-fragment per
// K-step) and converted in-register with cvt_pk — bit-identical to the old LDS path.
// All 4 waves read the same A rows -> L1 dedup. B comes from the permuted Bp table:
// one contiguous 1KB wave-transaction per fragment, 2-deep rotating prefetch.
// The A/S pass re-reads the tile from global (float2/thread, fully coalesced, L2-hot).
// No staging phase, no tile barrier, ~1KB LDS -> high occupancy, pure pipelined flow.
__global__ __launch_bounds__(256, 4) void attn_main(
    const float* __restrict__ memory, const float* __restrict__ state,
    const ushort_t* __restrict__ Bp, const ushort_t* __restrict__ CWT,
    const float* __restrict__ zconst, const float* __restrict__ v_a,
    float* __restrict__ zA, float* __restrict__ zS,
    float* __restrict__ zSsum, float* __restrict__ zStsum)
{
    const int blk = blockIdx.x;
    const int b  = blk >> 6;            // / NCHUNK
    const int c  = blk & (NCHUNK - 1);
    const int t0 = c * TTILE;
    const int tid = threadIdx.x;

    __shared__ __align__(16) float sw_raw[80];
    __shared__ __align__(16) float ep_s[4][TTILE];
    __shared__ __align__(16) float s_s[TTILE];
    float* sw = sw_raw + 1;   // sw[i] = state[t0-15+i]

    // state window [t0-15, t0+47], zero-padded at sequence ends
    for (int i = tid; i < TTILE + 31; i += 256) {
        const int t = t0 - 15 + i;
        sw[i] = (t >= 0 && t < Tt) ? state[b * Tt + t] : 0.0f;
    }

    const int lane = tid & 63;
    const int w    = tid >> 6;
    const int lm   = lane & 15;
    const int lq   = lane >> 4;
    const int ncol0 = w * 64 + lm;

    // Permuted-B pointers: contiguous 1KB per wave-load. Per step s add s*8192 ushorts.
    const ushort_t* bp0 = Bp + (size_t)(w * 4) * 512 + lane * 8;
    const ushort_t* bp1 = bp0 + 512;
    const ushort_t* bp2 = bp0 + 1024;
    const ushort_t* bp3 = bp0 + 1536;
    const ushort_t* cp0 = CWT + (size_t)(w * 4) * 512 + lane * 8;

    // 2-deep B prefetch: steps 0 and 1
    short8 bbuf[2][4];
    bbuf[0][0] = *(const short8*)(bp0);
    bbuf[0][1] = *(const short8*)(bp1);
    bbuf[0][2] = *(const short8*)(bp2);
    bbuf[0][3] = *(const short8*)(bp3);
    bbuf[1][0] = *(const short8*)(bp0 + 8192);
    bbuf[1][1] = *(const short8*)(bp1 + 8192);
    bbuf[1][2] = *(const short8*)(bp2 + 8192);
    bbuf[1][3] = *(const short8*)(bp3 + 8192);

    // Direct-global A row pointers (fp32): rows t0+lm and t0+16+lm, k-offset lq*8
    const float* gA0 = memory + ((size_t)b * Tt + t0 + lm) * ENCn + lq * 8;
    const float* gA1 = gA0 + 16 * ENCn;

    // A pipeline: load step 0 (fp32), convert to bf16 fragments
    float4 n00 = *(const float4*)(gA0);
    float4 n01 = *(const float4*)(gA0 + 4);
    float4 n10 = *(const float4*)(gA1);
    float4 n11 = *(const float4*)(gA1 + 4);

    f32x4 acc[2][4] = {};

    __syncthreads();     // sw ready (needed by conv step)

    S8 a0c, a1c;
    a0c.u[0] = cvt_pk(n00.x, n00.y); a0c.u[1] = cvt_pk(n00.z, n00.w);
    a0c.u[2] = cvt_pk(n01.x, n01.y); a0c.u[3] = cvt_pk(n01.z, n01.w);
    a1c.u[0] = cvt_pk(n10.x, n10.y); a1c.u[1] = cvt_pk(n10.z, n10.w);
    a1c.u[2] = cvt_pk(n11.x, n11.y); a1c.u[3] = cvt_pk(n11.z, n11.w);

    #pragma unroll
    for (int s = 0; s < 16; ++s) {
        // A for step s+1 from global (s=15 wraps: redundant reload of step 0)
        const int sa = ((s + 1) & 15) * 32;
        n00 = *(const float4*)(gA0 + sa);
        n01 = *(const float4*)(gA0 + sa + 4);
        n10 = *(const float4*)(gA1 + sa);
        n11 = *(const float4*)(gA1 + sa + 4);
        // MFMA with current A and bbuf[s&1]
        acc[0][0] = __builtin_amdgcn_mfma_f32_16x16x32_bf16(a0c.v, bbuf[s & 1][0], acc[0][0], 0, 0, 0);
        acc[0][1] = __builtin_amdgcn_mfma_f32_16x16x32_bf16(a0c.v, bbuf[s & 1][1], acc[0][1], 0, 0, 0);
        acc[0][2] = __builtin_amdgcn_mfma_f32_16x16x32_bf16(a0c.v, bbuf[s & 1][2], acc[0][2], 0, 0, 0);
        acc[0][3] = __builtin_amdgcn_mfma_f32_16x16x32_bf16(a0c.v, bbuf[s & 1][3], acc[0][3], 0, 0, 0);
        acc[1][0] = __builtin_amdgcn_mfma_f32_16x16x32_bf16(a1c.v, bbuf[s & 1][0], acc[1][0], 0, 0, 0);
        acc[1][1] = __builtin_amdgcn_mfma_f32_16x16x32_bf16(a1c.v, bbuf[s & 1][1], acc[1][1], 0, 0, 0);
        acc[1][2] = __builtin_amdgcn_mfma_f32_16x16x32_bf16(a1c.v, bbuf[s & 1][2], acc[1][2], 0, 0, 0);
        acc[1][3] = __builtin_amdgcn_mfma_f32_16x16x32_bf16(a1c.v, bbuf[s & 1][3], acc[1][3], 0, 0, 0);
        // B prefetch for step s+2 into the slot just consumed (wraps, L1-hot)
        const int sn = ((s + 2) & 15) * 8192;
        bbuf[s & 1][0] = *(const short8*)(bp0 + sn);
        bbuf[s & 1][1] = *(const short8*)(bp1 + sn);
        bbuf[s & 1][2] = *(const short8*)(bp2 + sn);
        bbuf[s & 1][3] = *(const short8*)(bp3 + sn);
        // convert next A
        a0c.u[0] = cvt_pk(n00.x, n00.y); a0c.u[1] = cvt_pk(n00.z, n00.w);
        a0c.u[2] = cvt_pk(n01.x, n01.y); a0c.u[3] = cvt_pk(n01.z, n01.w);
        a1c.u[0] = cvt_pk(n10.x, n10.y); a1c.u[1] = cvt_pk(n10.z, n10.w);
        a1c.u[2] = cvt_pk(n11.x, n11.y); a1c.u[3] = cvt_pk(n11.z, n11.w);
    }

    // conv as one extra K=32 MFMA step: A[t][k] = sw[t + k], B = CWT (permuted)
    {
        S8 ca0, ca1;
        #pragma unroll
        for (int j = 0; j < 4; ++j) {
            const int base0 = lm + lq * 8 + 2 * j;
            ca0.u[j] = cvt_pk(sw[base0],      sw[base0 + 1]);
            ca1.u[j] = cvt_pk(sw[base0 + 16], sw[base0 + 17]);
        }
        const short8 cb0 = *(const short8*)(cp0);
        const short8 cb1 = *(const short8*)(cp0 + 512);
        const short8 cb2 = *(const short8*)(cp0 + 1024);
        const short8 cb3 = *(const short8*)(cp0 + 1536);
        acc[0][0] = __builtin_amdgcn_mfma_f32_16x16x32_bf16(ca0.v, cb0, acc[0][0], 0, 0, 0);
        acc[0][1] = __builtin_amdgcn_mfma_f32_16x16x32_bf16(ca0.v, cb1, acc[0][1], 0, 0, 0);
        acc[0][2] = __builtin_amdgcn_mfma_f32_16x16x32_bf16(ca0.v, cb2, acc[0][2], 0, 0, 0);
        acc[0][3] = __builtin_amdgcn_mfma_f32_16x16x32_bf16(ca0.v, cb3, acc[0][3], 0, 0, 0);
        acc[1][0] = __builtin_amdgcn_mfma_f32_16x16x32_bf16(ca1.v, cb0, acc[1][0], 0, 0, 0);
        acc[1][1] = __builtin_amdgcn_mfma_f32_16x16x32_bf16(ca1.v, cb1, acc[1][1], 0, 0, 0);
        acc[1][2] = __builtin_amdgcn_mfma_f32_16x16x32_bf16(ca1.v, cb2, acc[1][2], 0, 0, 0);
        acc[1][3] = __builtin_amdgcn_mfma_f32_16x16x32_bf16(ca1.v, cb3, acc[1][3], 0, 0, 0);
    }

    // epilogue: zconst + tanh + v_a dot; reduce over the 16 n-lanes
    float zc[4], va[4];
    #pragma unroll
    for (int nbi = 0; nbi < 4; ++nbi) {
        const int col = ncol0 + nbi * 16;
        zc[nbi] = zconst[b * Un + col];
        va[nbi] = v_a[col];
    }
    #pragma unroll
    for (int mb = 0; mb < 2; ++mb) {
        #pragma unroll
        for (int r = 0; r < 4; ++r) {
            float ep = 0.f;
            #pragma unroll
            for (int nbi = 0; nbi < 4; ++nbi)
                ep += tanh_fast(acc[mb][nbi][r] + zc[nbi]) * va[nbi];
            ep += __shfl_xor(ep, 1, 64);
            ep += __shfl_xor(ep, 2, 64);
            ep += __shfl_xor(ep, 4, 64);
            ep += __shfl_xor(ep, 8, 64);
            if (lm == 0) ep_s[w][mb * 16 + lq * 4 + r] = ep;   // C/D: row = quad*4+reg
        }
    }
    __syncthreads();

    if (tid < 64) {
        float s = 0.f, st = 0.f;
        if (tid < TTILE) {
            const float energy = ep_s[0][tid] + ep_s[1][tid] + ep_s[2][tid] + ep_s[3][tid];
            s = __builtin_amdgcn_rcpf(1.0f + __expf(-energy));
            s_s[tid] = s;
            st = sw[15 + tid];
        }
        float ssum = s, stsum = st;
        #pragma unroll
        for (int off = 32; off >= 1; off >>= 1) {
            ssum  += __shfl_xor(ssum,  off, 64);
            stsum += __shfl_xor(stsum, off, 64);
        }
        if (tid == 0) {
            atomicAdd(&zSsum[b], ssum);
            atomicAdd(&zStsum[b], stsum);
        }
    }
    __syncthreads();

    // A/S weighted accumulation straight from global (L2-hot tile, fp32, coalesced):
    // thread owns e = 2*tid, 2*tid+1
    const int e0 = tid << 1;
    const float* gM = memory + ((size_t)b * Tt + t0) * ENCn + e0;
    float aA0 = 0.f, aA1 = 0.f, aS0 = 0.f, aS1 = 0.f;
    #pragma unroll 4
    for (int r = 0; r < TTILE; ++r) {
        const float2 mm = *(const float2*)(gM + (size_t)r * ENCn);
        const float st = sw[15 + r];
        const float sv = s_s[r];
        aA0 += st * mm.x; aA1 += st * mm.y;
        aS0 += sv * mm.x; aS1 += sv * mm.y;
    }
    atomicAdd(&zA[b * ENCn + e0],     aA0);
    atomicAdd(&zA[b * ENCn + e0 + 1], aA1);
    atomicAdd(&zS[b * ENCn + e0],     aS0);
    atomicAdd(&zS[b * ENCn + e0 + 1], aS1);
}

// ---------------- finalize ----------------
__global__ void k_final(const float* __restrict__ zA, const float* __restrict__ zS,
                        const float* __restrict__ zSsum, const float* __restrict__ zStsum,
                        const float* __restrict__ Wm, const float* __restrict__ bm,
                        float* __restrict__ out)
{
    const int b = blockIdx.x, e0 = blockIdx.y * 128, u = threadIdx.x;
    const float inv = 1.0f / zSsum[b];
    float a0 = 0.f, a1 = 0.f;
    #pragma unroll 4
    for (int e = e0; e < e0 + 128; e += 2) {
        const float c0 = zA[b * ENCn + e]     + zS[b * ENCn + e]     * inv;
        const float c1 = zA[b * ENCn + e + 1] + zS[b * ENCn + e + 1] * inv;
        a0 += c0 * Wm[(size_t)e * Un + u];
        a1 += c1 * Wm[(size_t)(e + 1) * Un + u];
    }
    float acc = a0 + a1;
    if (blockIdx.y == 0) acc += bm[u] * (zStsum[b] + 1.0f);
    atomicAdd(&out[b * Un + u], acc);
}

// ---------------- launch ----------------
extern "C" void kernel_launch(void* const* d_in, const int* in_sizes, int n_in,
                              void* d_out, int out_size, void* d_ws, size_t ws_size,
                              hipStream_t stream)
{
    const float* query  = (const float*)d_in[0];
    const float* state  = (const float*)d_in[1];
    const float* memory = (const float*)d_in[2];
    const float* Wq     = (const float*)d_in[3];
    const float* bq     = (const float*)d_in[4];
    const float* Wm     = (const float*)d_in[5];
    const float* bm     = (const float*)d_in[6];
    const float* Wl     = (const float*)d_in[7];
    const float* bl     = (const float*)d_in[8];
    const float* conv_w = (const float*)d_in[9];
    const float* conv_b = (const float*)d_in[10];
    const float* We     = (const float*)d_in[11];
    const float* be     = (const float*)d_in[12];
    const float* v_a    = (const float*)d_in[13];
    float* out = (float*)d_out;

    // workspace layout (float offsets)
    float* ws      = (float*)d_ws;
    float* zA      = ws;                   // 32768
    float* zS      = ws + 32768;           // 32768
    float* zSsum   = ws + 65536;           // 64
    float* zStsum  = ws + 65600;           // 64
    float* g_      = ws + 65664;           // 16384 (atomic-accumulated)
    float* zconst  = ws + 82048;           // 16384 (atomic-accumulated) -> zero ends 98432
    float* cvec    = ws + 98432;           // 256
    ushort_t* Bp    = (ushort_t*)(ws + 98688);   // 131072 ushorts (permuted WmWeT)
    ushort_t* CWT   = (ushort_t*)(ws + 164224);  // 8192 ushorts (permuted)

    hipMemsetAsync(ws, 0, 98432 * sizeof(float), stream);
    hipMemsetAsync(out, 0, (size_t)Bq * Un * sizeof(float), stream);

    hipLaunchKernelGGL(k_prep1, dim3(517), dim3(Un), 0, stream,
                       We, Wm, Wl, conv_w, bq, bm, bl, conv_b, Bp, CWT, cvec);
    hipLaunchKernelGGL(k_g, dim3(Bq, 8), dim3(Un), 0, stream, query, Wq, cvec, g_);
    hipLaunchKernelGGL(k_zconst, dim3(Bq, 4), dim3(Un), 0, stream, g_, We, be, zconst);
    hipLaunchKernelGGL(attn_main, dim3(Bq * NCHUNK), dim3(256), 0, stream,
                       memory, state, Bp, CWT, zconst, v_a, zA, zS, zSsum, zStsum);
    hipLaunchKernelGGL(k_final, dim3(Bq, 4), dim3(Un), 0, stream,
                       zA, zS, zSsum, zStsum, Wm, bm, out);
}

// Round 5
// 577.505 us; speedup vs baseline: 1.2580x; 1.0535x over previous
//
#include <hip/hip_runtime.h>
#include <hip/hip_bf16.h>
#include <math.h>

// Problem constants
#define Bq 64
#define Tt 2048
#define TQn 2
#define HIDn 1024
#define ENCn 512
#define Un 256
#define FILTn 32
#define KKn 31

// Main-pass tiling
#define TTILE 64
#define NCHUNK (Tt / TTILE)     // 32

typedef short short8 __attribute__((ext_vector_type(8)));
typedef float f32x4  __attribute__((ext_vector_type(4)));
typedef unsigned short ushort_t;
typedef unsigned int   uint_t;

union S8 { short8 v; uint_t u[4]; };

__device__ __forceinline__ ushort_t f2b(float f) {          // RNE scalar (prep only)
    union { float f; uint_t u; } x; x.f = f;
    uint_t r = x.u + 0x7fffu + ((x.u >> 16) & 1u);
    return (ushort_t)(r >> 16);
}
__device__ __forceinline__ uint_t cvt_pk(float lo, float hi) {  // HW v_cvt_pk_bf16_f32
    union { __hip_bfloat162 h; uint_t u; } x;
    x.h = __float22bfloat162_rn(make_float2(lo, hi));
    return x.u;
}
__device__ __forceinline__ float tanh_fast(float x) {
    const float e = __expf(2.0f * x);
    return 1.0f - 2.0f * __builtin_amdgcn_rcpf(e + 1.0f);
}

// B-layout helper: element (v, k) of WmWe^T goes to the slot wave-load order expects:
// seg = (k>>5)*16 + (v>>6)*4 + ((v>>4)&3), lane = ((k>>3)&3)*16 + (v&15), j = k&7
// ushort idx = seg*512 + lane*8 + j   -> every wave B-load is one contiguous 1KB txn.
__device__ __forceinline__ int bp_idx(int v, int k) {
    const int seg = (k >> 5) * 16 + (v >> 6) * 4 + ((v >> 4) & 3);
    const int ln  = ((k >> 3) & 3) * 16 + (v & 15);
    return seg * 512 + ln * 8 + (k & 7);
}

// ---------------- k_prep: Bp (512 blks) + CWT (4 blks) + per-b g/zconst chain (64 blks) ----
__global__ void k_prep(const float* __restrict__ We, const float* __restrict__ Wm,
                       const float* __restrict__ Wl, const float* __restrict__ conv_w,
                       const float* __restrict__ bq, const float* __restrict__ bm,
                       const float* __restrict__ bl, const float* __restrict__ conv_b,
                       const float* __restrict__ query, const float* __restrict__ Wq,
                       const float* __restrict__ be,
                       ushort_t* __restrict__ Bp, ushort_t* __restrict__ CWT,
                       float* __restrict__ zconst)
{
    const int blk = blockIdx.x;
    __shared__ float wlwe[FILTn * 64];     // CWT branch
    __shared__ float g_lds[Un];            // gz branch
    if (blk < 512) {               // Bp slot for (v, k=e) = bf16(sum_u Wm[e,u] We[u,v])
        const int v = threadIdx.x;
        const int e = blk;
        float a0 = 0.f, a1 = 0.f, a2 = 0.f, a3 = 0.f;
        #pragma unroll 4
        for (int u = 0; u < Un; u += 4) {
            a0 += Wm[(size_t)e * Un + u + 0] * We[(u + 0) * Un + v];
            a1 += Wm[(size_t)e * Un + u + 1] * We[(u + 1) * Un + v];
            a2 += Wm[(size_t)e * Un + u + 2] * We[(u + 2) * Un + v];
            a3 += Wm[(size_t)e * Un + u + 3] * We[(u + 3) * Un + v];
        }
        Bp[bp_idx(v, e)] = f2b((a0 + a1) + (a2 + a3));
    } else if (blk < 516) {        // CWT (permuted, k<32) for a 64-wide v chunk
        const int vc = (blk - 512) * 64;
        for (int i = threadIdx.x; i < FILTn * 64; i += 256) {
            const int f = i >> 6, vv = i & 63;
            float a = 0.f;
            #pragma unroll 8
            for (int u = 0; u < Un; ++u) a += Wl[f * Un + u] * We[u * Un + vc + vv];
            wlwe[f * 64 + vv] = a;
        }
        __syncthreads();
        for (int i = threadIdx.x; i < 64 * 32; i += 256) {
            const int vv = i >> 5, k = i & 31;
            float a = 0.f;
            if (k < KKn) {
                #pragma unroll
                for (int f = 0; f < FILTn; ++f) a += conv_w[f * KKn + k] * wlwe[f * 64 + vv];
            }
            CWT[bp_idx(vc + vv, k)] = f2b(a);
        }
    } else {                       // per-b chain: cvec (reg) -> g (LDS) -> zconst (global)
        const int b = blk - 516;
        const int u = threadIdx.x;
        float cv = bq[u] + bm[u] + bl[u];
        #pragma unroll
        for (int f = 0; f < FILTn; ++f) cv += conv_b[f] * Wl[f * Un + u];
        const float* q = query + ((size_t)b * TQn + 1) * HIDn;
        float a0 = 0.f, a1 = 0.f, a2 = 0.f, a3 = 0.f;
        #pragma unroll 4
        for (int h = 0; h < HIDn; h += 4) {
            a0 += q[h + 0] * Wq[(size_t)(h + 0) * Un + u];
            a1 += q[h + 1] * Wq[(size_t)(h + 1) * Un + u];
            a2 += q[h + 2] * Wq[(size_t)(h + 2) * Un + u];
            a3 += q[h + 3] * Wq[(size_t)(h + 3) * Un + u];
        }
        g_lds[u] = cv + (a0 + a1) + (a2 + a3);
        __syncthreads();
        float z0 = 0.f, z1 = 0.f;
        #pragma unroll 4
        for (int uu = 0; uu < Un; uu += 2) {
            z0 += g_lds[uu]     * We[(size_t)uu * Un + u];
            z1 += g_lds[uu + 1] * We[(size_t)(uu + 1) * Un + u];
        }
        zconst[b * Un + u] = be[u] + z0 + z1;
    }
}

// ---------------- main fused MFMA pass (M=64, direct-global A, permuted B) ----------------
// Block = (b, 64-row t-chunk), 256 thr = 4 waves; wave w owns v-cols w*64..w*64+63.
// 4 m-fragments per wave (rows t0+lm+16i) -> each B fragment feeds 16 MFMAs (2x the
// per-B work of the 32-row version), halving B traffic and doubling latency cover.
// A fragments read straight from global fp32 and converted with cvt_pk in-register.
// The A/S pass re-reads the tile from global (fp32, coalesced, L3-hot).
__global__ __launch_bounds__(256, 3) void attn_main(
    const float* __restrict__ memory, const float* __restrict__ state,
    const ushort_t* __restrict__ Bp, const ushort_t* __restrict__ CWT,
    const float* __restrict__ zconst, const float* __restrict__ v_a,
    float* __restrict__ zA, float* __restrict__ zS,
    float* __restrict__ zSsum, float* __restrict__ zStsum)
{
    const int blk = blockIdx.x;
    const int b  = blk >> 5;            // / NCHUNK
    const int c  = blk & (NCHUNK - 1);
    const int t0 = c * TTILE;
    const int tid = threadIdx.x;

    __shared__ __align__(16) float sw_raw[TTILE + 36];
    __shared__ __align__(16) float ep_s[4][TTILE];
    __shared__ __align__(16) float s_s[TTILE];
    float* sw = sw_raw + 1;   // sw[i] = state[t0-15+i], i in [0, TTILE+31)

    // state window [t0-15, t0+TTILE+15], zero-padded at sequence ends
    for (int i = tid; i < TTILE + 31; i += 256) {
        const int t = t0 - 15 + i;
        sw[i] = (t >= 0 && t < Tt) ? state[b * Tt + t] : 0.0f;
    }

    const int lane = tid & 63;
    const int w    = tid >> 6;
    const int lm   = lane & 15;
    const int lq   = lane >> 4;
    const int ncol0 = w * 64 + lm;

    // Permuted-B pointers: contiguous 1KB per wave-load. Per step s add s*8192 ushorts.
    const ushort_t* bp0 = Bp + (size_t)(w * 4) * 512 + lane * 8;
    const ushort_t* bp1 = bp0 + 512;
    const ushort_t* bp2 = bp0 + 1024;
    const ushort_t* bp3 = bp0 + 1536;
    const ushort_t* cp0 = CWT + (size_t)(w * 4) * 512 + lane * 8;

    // 2-deep B prefetch: steps 0 and 1
    short8 bbuf[2][4];
    bbuf[0][0] = *(const short8*)(bp0);
    bbuf[0][1] = *(const short8*)(bp1);
    bbuf[0][2] = *(const short8*)(bp2);
    bbuf[0][3] = *(const short8*)(bp3);
    bbuf[1][0] = *(const short8*)(bp0 + 8192);
    bbuf[1][1] = *(const short8*)(bp1 + 8192);
    bbuf[1][2] = *(const short8*)(bp2 + 8192);
    bbuf[1][3] = *(const short8*)(bp3 + 8192);

    // Direct-global A: 4 row-fragments, rows t0 + lm + 16*i, k-offset lq*8
    const float* gAb = memory + ((size_t)b * Tt + t0 + lm) * ENCn + lq * 8;

    // A pipeline: load step 0
    float4 nx[4][2];
    #pragma unroll
    for (int i = 0; i < 4; ++i) {
        nx[i][0] = *(const float4*)(gAb + (size_t)i * 16 * ENCn);
        nx[i][1] = *(const float4*)(gAb + (size_t)i * 16 * ENCn + 4);
    }

    f32x4 acc[4][4] = {};

    __syncthreads();     // sw ready (needed by conv step)

    S8 af[4];
    #pragma unroll
    for (int i = 0; i < 4; ++i) {
        af[i].u[0] = cvt_pk(nx[i][0].x, nx[i][0].y);
        af[i].u[1] = cvt_pk(nx[i][0].z, nx[i][0].w);
        af[i].u[2] = cvt_pk(nx[i][1].x, nx[i][1].y);
        af[i].u[3] = cvt_pk(nx[i][1].z, nx[i][1].w);
    }

    #pragma unroll
    for (int s = 0; s < 16; ++s) {
        // A for step s+1 from global (s=15 wraps: redundant reload of step 0)
        const int sa = ((s + 1) & 15) * 32;
        #pragma unroll
        for (int i = 0; i < 4; ++i) {
            nx[i][0] = *(const float4*)(gAb + (size_t)i * 16 * ENCn + sa);
            nx[i][1] = *(const float4*)(gAb + (size_t)i * 16 * ENCn + sa + 4);
        }
        // 16 MFMAs with current A and bbuf[s&1]
        #pragma unroll
        for (int i = 0; i < 4; ++i) {
            #pragma unroll
            for (int n = 0; n < 4; ++n)
                acc[i][n] = __builtin_amdgcn_mfma_f32_16x16x32_bf16(af[i].v, bbuf[s & 1][n], acc[i][n], 0, 0, 0);
        }
        // B prefetch for step s+2 into the slot just consumed
        const int sn = ((s + 2) & 15) * 8192;
        bbuf[s & 1][0] = *(const short8*)(bp0 + sn);
        bbuf[s & 1][1] = *(const short8*)(bp1 + sn);
        bbuf[s & 1][2] = *(const short8*)(bp2 + sn);
        bbuf[s & 1][3] = *(const short8*)(bp3 + sn);
        // convert next A
        #pragma unroll
        for (int i = 0; i < 4; ++i) {
            af[i].u[0] = cvt_pk(nx[i][0].x, nx[i][0].y);
            af[i].u[1] = cvt_pk(nx[i][0].z, nx[i][0].w);
            af[i].u[2] = cvt_pk(nx[i][1].x, nx[i][1].y);
            af[i].u[3] = cvt_pk(nx[i][1].z, nx[i][1].w);
        }
    }

    // conv as one extra K=32 MFMA step: A[t][k] = sw[t + k], B = CWT (permuted)
    {
        S8 ca[4];
        #pragma unroll
        for (int i = 0; i < 4; ++i) {
            #pragma unroll
            for (int j = 0; j < 4; ++j) {
                const int base0 = lm + 16 * i + lq * 8 + 2 * j;
                ca[i].u[j] = cvt_pk(sw[base0], sw[base0 + 1]);
            }
        }
        const short8 cb0 = *(const short8*)(cp0);
        const short8 cb1 = *(const short8*)(cp0 + 512);
        const short8 cb2 = *(const short8*)(cp0 + 1024);
        const short8 cb3 = *(const short8*)(cp0 + 1536);
        #pragma unroll
        for (int i = 0; i < 4; ++i) {
            acc[i][0] = __builtin_amdgcn_mfma_f32_16x16x32_bf16(ca[i].v, cb0, acc[i][0], 0, 0, 0);
            acc[i][1] = __builtin_amdgcn_mfma_f32_16x16x32_bf16(ca[i].v, cb1, acc[i][1], 0, 0, 0);
            acc[i][2] = __builtin_amdgcn_mfma_f32_16x16x32_bf16(ca[i].v, cb2, acc[i][2], 0, 0, 0);
            acc[i][3] = __builtin_amdgcn_mfma_f32_16x16x32_bf16(ca[i].v, cb3, acc[i][3], 0, 0, 0);
        }
    }

    // epilogue: zconst + tanh + v_a dot; reduce over the 16 n-lanes
    float zc[4], va[4];
    #pragma unroll
    for (int nbi = 0; nbi < 4; ++nbi) {
        const int col = ncol0 + nbi * 16;
        zc[nbi] = zconst[b * Un + col];
        va[nbi] = v_a[col];
    }
    #pragma unroll
    for (int i = 0; i < 4; ++i) {
        #pragma unroll
        for (int r = 0; r < 4; ++r) {
            float ep = 0.f;
            #pragma unroll
            for (int nbi = 0; nbi < 4; ++nbi)
                ep += tanh_fast(acc[i][nbi][r] + zc[nbi]) * va[nbi];
            ep += __shfl_xor(ep, 1, 64);
            ep += __shfl_xor(ep, 2, 64);
            ep += __shfl_xor(ep, 4, 64);
            ep += __shfl_xor(ep, 8, 64);
            if (lm == 0) ep_s[w][i * 16 + lq * 4 + r] = ep;   // C/D: row = quad*4+reg
        }
    }
    __syncthreads();

    if (tid < 64) {
        const float energy = ep_s[0][tid] + ep_s[1][tid] + ep_s[2][tid] + ep_s[3][tid];
        const float s = __builtin_amdgcn_rcpf(1.0f + __expf(-energy));
        s_s[tid] = s;
        const float st = sw[15 + tid];
        float ssum = s, stsum = st;
        #pragma unroll
        for (int off = 32; off >= 1; off >>= 1) {
            ssum  += __shfl_xor(ssum,  off, 64);
            stsum += __shfl_xor(stsum, off, 64);
        }
        if (tid == 0) {
            atomicAdd(&zSsum[b], ssum);
            atomicAdd(&zStsum[b], stsum);
        }
    }
    __syncthreads();

    // A/S weighted accumulation straight from global (L3-hot tile, fp32, coalesced):
    // thread owns e = 2*tid, 2*tid+1
    const int e0 = tid << 1;
    const float* gM = memory + ((size_t)b * Tt + t0) * ENCn + e0;
    float aA0 = 0.f, aA1 = 0.f, aS0 = 0.f, aS1 = 0.f;
    #pragma unroll 2
    for (int r4 = 0; r4 < TTILE / 4; ++r4) {
        const float4 sv4 = *(const float4*)&s_s[r4 * 4];
        const float4 st4 = *(const float4*)&sw[15 + r4 * 4];
        const float sv[4] = {sv4.x, sv4.y, sv4.z, sv4.w};
        const float st[4] = {st4.x, st4.y, st4.z, st4.w};
        #pragma unroll
        for (int j = 0; j < 4; ++j) {
            const int r = r4 * 4 + j;
            const float2 mm = *(const float2*)(gM + (size_t)r * ENCn);
            aA0 += st[j] * mm.x; aA1 += st[j] * mm.y;
            aS0 += sv[j] * mm.x; aS1 += sv[j] * mm.y;
        }
    }
    atomicAdd(&zA[b * ENCn + e0],     aA0);
    atomicAdd(&zA[b * ENCn + e0 + 1], aA1);
    atomicAdd(&zS[b * ENCn + e0],     aS0);
    atomicAdd(&zS[b * ENCn + e0 + 1], aS1);
}

// ---------------- finalize ----------------
__global__ void k_final(const float* __restrict__ zA, const float* __restrict__ zS,
                        const float* __restrict__ zSsum, const float* __restrict__ zStsum,
                        const float* __restrict__ Wm, const float* __restrict__ bm,
                        float* __restrict__ out)
{
    const int b = blockIdx.x, e0 = blockIdx.y * 128, u = threadIdx.x;
    const float inv = 1.0f / zSsum[b];
    float a0 = 0.f, a1 = 0.f;
    #pragma unroll 4
    for (int e = e0; e < e0 + 128; e += 2) {
        const float c0 = zA[b * ENCn + e]     + zS[b * ENCn + e]     * inv;
        const float c1 = zA[b * ENCn + e + 1] + zS[b * ENCn + e + 1] * inv;
        a0 += c0 * Wm[(size_t)e * Un + u];
        a1 += c1 * Wm[(size_t)(e + 1) * Un + u];
    }
    float acc = a0 + a1;
    if (blockIdx.y == 0) acc += bm[u] * (zStsum[b] + 1.0f);
    atomicAdd(&out[b * Un + u], acc);
}

// ---------------- launch ----------------
extern "C" void kernel_launch(void* const* d_in, const int* in_sizes, int n_in,
                              void* d_out, int out_size, void* d_ws, size_t ws_size,
                              hipStream_t stream)
{
    const float* query  = (const float*)d_in[0];
    const float* state  = (const float*)d_in[1];
    const float* memory = (const float*)d_in[2];
    const float* Wq     = (const float*)d_in[3];
    const float* bq     = (const float*)d_in[4];
    const float* Wm     = (const float*)d_in[5];
    const float* bm     = (const float*)d_in[6];
    const float* Wl     = (const float*)d_in[7];
    const float* bl     = (const float*)d_in[8];
    const float* conv_w = (const float*)d_in[9];
    const float* conv_b = (const float*)d_in[10];
    const float* We     = (const float*)d_in[11];
    const float* be     = (const float*)d_in[12];
    const float* v_a    = (const float*)d_in[13];
    float* out = (float*)d_out;

    // workspace layout (float offsets)
    float* ws      = (float*)d_ws;
    float* zA      = ws;                   // 32768
    float* zS      = ws + 32768;           // 32768
    float* zSsum   = ws + 65536;           // 64
    float* zStsum  = ws + 65600;           // 64 -> zero ends 65664
    float* zconst  = ws + 65664;           // 16384 (direct-written, no memset needed)
    ushort_t* Bp    = (ushort_t*)(ws + 82048);   // 131072 ushorts (permuted WmWeT)
    ushort_t* CWT   = (ushort_t*)(ws + 147584);  // 8192 ushorts (permuted)

    hipMemsetAsync(ws, 0, 65664 * sizeof(float), stream);
    hipMemsetAsync(out, 0, (size_t)Bq * Un * sizeof(float), stream);

    hipLaunchKernelGGL(k_prep, dim3(516 + Bq), dim3(Un), 0, stream,
                       We, Wm, Wl, conv_w, bq, bm, bl, conv_b, query, Wq, be,
                       Bp, CWT, zconst);
    hipLaunchKernelGGL(attn_main, dim3(Bq * NCHUNK), dim3(256), 0, stream,
                       memory, state, Bp, CWT, zconst, v_a, zA, zS, zSsum, zStsum);
    hipLaunchKernelGGL(k_final, dim3(Bq, 4), dim3(Un), 0, stream,
                       zA, zS, zSsum, zStsum, Wm, bm, out);
}

// Round 6
// 516.631 us; speedup vs baseline: 1.4063x; 1.1178x over previous
//
#include <hip/hip_runtime.h>
#include <hip/hip_bf16.h>
#include <math.h>

// Problem constants
#define Bq 64
#define Tt 2048
#define TQn 2
#define HIDn 1024
#define ENCn 512
#define Un 256
#define FILTn 32
#define KKn 31

// Main-pass tiling
#define TTILE 32
#define NCHUNK (Tt / TTILE)     // 64
#define LDK 520                 // padded LDS row (bf16): 512+8, 16B-aligned rows

typedef short short8 __attribute__((ext_vector_type(8)));
typedef float f32x4  __attribute__((ext_vector_type(4)));
typedef float f32x4v __attribute__((ext_vector_type(4)));
typedef unsigned short ushort_t;
typedef unsigned int   uint_t;

union S8 { short8 v; uint_t u[4]; };

__device__ __forceinline__ ushort_t f2b(float f) {          // RNE scalar (prep only)
    union { float f; uint_t u; } x; x.f = f;
    uint_t r = x.u + 0x7fffu + ((x.u >> 16) & 1u);
    return (ushort_t)(r >> 16);
}
__device__ __forceinline__ uint_t cvt_pk(float lo, float hi) {  // HW v_cvt_pk_bf16_f32
    union { __hip_bfloat162 h; uint_t u; } x;
    x.h = __float22bfloat162_rn(make_float2(lo, hi));
    return x.u;
}
__device__ __forceinline__ float b2f(uint_t u16) {
    union { uint_t i; float f; } x; x.i = u16 << 16;
    return x.f;
}
__device__ __forceinline__ float tanh_fast(float x) {
    const float e = __expf(2.0f * x);
    return 1.0f - 2.0f * __builtin_amdgcn_rcpf(e + 1.0f);
}

// B-layout helper: element (v, k) of WmWe^T goes to the slot wave-load order expects:
// seg = (k>>5)*16 + (v>>6)*4 + ((v>>4)&3), lane = ((k>>3)&3)*16 + (v&15), j = k&7
// ushort idx = seg*512 + lane*8 + j   -> every wave B-load is one contiguous 1KB txn.
__device__ __forceinline__ int bp_idx(int v, int k) {
    const int seg = (k >> 5) * 16 + (v >> 6) * 4 + ((v >> 4) & 3);
    const int ln  = ((k >> 3) & 3) * 16 + (v & 15);
    return seg * 512 + ln * 8 + (k & 7);
}

// ---------------- k_prep: Bp (512 blks) + CWT (4 blks) + per-b g/zconst chain (64 blks) ----
__global__ void k_prep(const float* __restrict__ We, const float* __restrict__ Wm,
                       const float* __restrict__ Wl, const float* __restrict__ conv_w,
                       const float* __restrict__ bq, const float* __restrict__ bm,
                       const float* __restrict__ bl, const float* __restrict__ conv_b,
                       const float* __restrict__ query, const float* __restrict__ Wq,
                       const float* __restrict__ be,
                       ushort_t* __restrict__ Bp, ushort_t* __restrict__ CWT,
                       float* __restrict__ zconst)
{
    const int blk = blockIdx.x;
    __shared__ float wlwe[FILTn * 64];     // CWT branch
    __shared__ float g_lds[Un];            // gz branch
    if (blk < 512) {               // Bp slot for (v, k=e) = bf16(sum_u Wm[e,u] We[u,v])
        const int v = threadIdx.x;
        const int e = blk;
        float a0 = 0.f, a1 = 0.f, a2 = 0.f, a3 = 0.f;
        #pragma unroll 4
        for (int u = 0; u < Un; u += 4) {
            a0 += Wm[(size_t)e * Un + u + 0] * We[(u + 0) * Un + v];
            a1 += Wm[(size_t)e * Un + u + 1] * We[(u + 1) * Un + v];
            a2 += Wm[(size_t)e * Un + u + 2] * We[(u + 2) * Un + v];
            a3 += Wm[(size_t)e * Un + u + 3] * We[(u + 3) * Un + v];
        }
        Bp[bp_idx(v, e)] = f2b((a0 + a1) + (a2 + a3));
    } else if (blk < 516) {        // CWT (permuted, k<32) for a 64-wide v chunk
        const int vc = (blk - 512) * 64;
        for (int i = threadIdx.x; i < FILTn * 64; i += 256) {
            const int f = i >> 6, vv = i & 63;
            float a = 0.f;
            #pragma unroll 8
            for (int u = 0; u < Un; ++u) a += Wl[f * Un + u] * We[u * Un + vc + vv];
            wlwe[f * 64 + vv] = a;
        }
        __syncthreads();
        for (int i = threadIdx.x; i < 64 * 32; i += 256) {
            const int vv = i >> 5, k = i & 31;
            float a = 0.f;
            if (k < KKn) {
                #pragma unroll
                for (int f = 0; f < FILTn; ++f) a += conv_w[f * KKn + k] * wlwe[f * 64 + vv];
            }
            CWT[bp_idx(vc + vv, k)] = f2b(a);
        }
    } else {                       // per-b chain: cvec (reg) -> g (LDS) -> zconst (global)
        const int b = blk - 516;
        const int u = threadIdx.x;
        float cv = bq[u] + bm[u] + bl[u];
        #pragma unroll
        for (int f = 0; f < FILTn; ++f) cv += conv_b[f] * Wl[f * Un + u];
        const float* q = query + ((size_t)b * TQn + 1) * HIDn;
        float a0 = 0.f, a1 = 0.f, a2 = 0.f, a3 = 0.f;
        #pragma unroll 4
        for (int h = 0; h < HIDn; h += 4) {
            a0 += q[h + 0] * Wq[(size_t)(h + 0) * Un + u];
            a1 += q[h + 1] * Wq[(size_t)(h + 1) * Un + u];
            a2 += q[h + 2] * Wq[(size_t)(h + 2) * Un + u];
            a3 += q[h + 3] * Wq[(size_t)(h + 3) * Un + u];
        }
        g_lds[u] = cv + (a0 + a1) + (a2 + a3);
        __syncthreads();
        float z0 = 0.f, z1 = 0.f;
        #pragma unroll 4
        for (int uu = 0; uu < Un; uu += 2) {
            z0 += g_lds[uu]     * We[(size_t)uu * Un + u];
            z1 += g_lds[uu + 1] * We[(size_t)(uu + 1) * Un + u];
        }
        zconst[b * Un + u] = be[u] + z0 + z1;
    }
}

// ---------------- main fused MFMA pass (LDS-staged tile, nt streaming, permuted B) -------
// Block: (b, 32-row t-chunk), 256 thr = 4 waves; wave w owns v-cols w*64..w*64+63.
// Staging reads the memory tensor with NON-TEMPORAL loads (row-contiguous, full-line)
// to avoid allocating a 268MB stream through the 256MB L3 (LRU thrash). The bf16 tile
// lives in LDS and serves both the MFMA A-operand and the A/S weighted pass.
// B table (Bp) is permuted so each wave B-load is one contiguous 1KB transaction.
__global__ __launch_bounds__(256, 4) void attn_main(
    const float* __restrict__ memory, const float* __restrict__ state,
    const ushort_t* __restrict__ Bp, const ushort_t* __restrict__ CWT,
    const float* __restrict__ zconst, const float* __restrict__ v_a,
    float* __restrict__ zA, float* __restrict__ zS,
    float* __restrict__ zSsum, float* __restrict__ zStsum)
{
    const int blk = blockIdx.x;
    const int b  = blk >> 6;            // / NCHUNK
    const int c  = blk & (NCHUNK - 1);
    const int t0 = c * TTILE;
    const int tid = threadIdx.x;

    __shared__ __align__(16) ushort_t mem_s[TTILE * LDK];   // 33280 B
    __shared__ __align__(16) float sw_raw[80];
    __shared__ __align__(16) float ep_s[4][TTILE];
    __shared__ __align__(16) float s_s[TTILE];
    float* sw = sw_raw + 1;   // sw[i] = state[t0-15+i]

    // state window [t0-15, t0+47], zero-padded at sequence ends
    for (int i = tid; i < TTILE + 31; i += 256) {
        const int t = t0 - 15 + i;
        sw[i] = (t >= 0 && t < Tt) ? state[b * Tt + t] : 0.0f;
    }

    const int lane = tid & 63;
    const int w    = tid >> 6;
    const int lm   = lane & 15;
    const int lq   = lane >> 4;
    const int ncol0 = w * 64 + lm;

    // Permuted-B pointers: contiguous 1KB per wave-load. Per step s add s*8192 ushorts.
    const ushort_t* bp0 = Bp + (size_t)(w * 4) * 512 + lane * 8;
    const ushort_t* bp1 = bp0 + 512;
    const ushort_t* bp2 = bp0 + 1024;
    const ushort_t* bp3 = bp0 + 1536;
    const ushort_t* cp0 = CWT + (size_t)(w * 4) * 512 + lane * 8;

    // 2-deep B prefetch: steps 0 and 1 issued before the staging barrier
    short8 bbuf[2][4];
    bbuf[0][0] = *(const short8*)(bp0);
    bbuf[0][1] = *(const short8*)(bp1);
    bbuf[0][2] = *(const short8*)(bp2);
    bbuf[0][3] = *(const short8*)(bp3);
    bbuf[1][0] = *(const short8*)(bp0 + 8192);
    bbuf[1][1] = *(const short8*)(bp1 + 8192);
    bbuf[1][2] = *(const short8*)(bp2 + 8192);
    bbuf[1][3] = *(const short8*)(bp3 + 8192);

    // stage 32x512 fp32 -> bf16 LDS tile (non-temporal, row-contiguous)
    const f32x4v* memv4 = (const f32x4v*)(memory + ((size_t)b * Tt + t0) * ENCn);
    #pragma unroll
    for (int i = 0; i < 8; ++i) {
        const int idx = i * 256 + tid;          // 8-float chunk id, 0..2047
        const int row = idx >> 6;               // 64 chunks per row
        const int cw8 = (idx & 63) << 3;
        const f32x4v m0 = __builtin_nontemporal_load(memv4 + 2 * idx);
        const f32x4v m1 = __builtin_nontemporal_load(memv4 + 2 * idx + 1);
        S8 v;
        v.u[0] = cvt_pk(m0.x, m0.y); v.u[1] = cvt_pk(m0.z, m0.w);
        v.u[2] = cvt_pk(m1.x, m1.y); v.u[3] = cvt_pk(m1.z, m1.w);
        *(short8*)&mem_s[row * LDK + cw8] = v.v;
    }

    f32x4 acc[2][4] = {};

    __syncthreads();

    const ushort_t* arow0 = &mem_s[(lm) * LDK + lq * 8];
    const ushort_t* arow1 = &mem_s[(16 + lm) * LDK + lq * 8];

    // A pipeline: load step 0
    short8 a0c = *(const short8*)(arow0);
    short8 a1c = *(const short8*)(arow1);

    #pragma unroll
    for (int s = 0; s < 16; ++s) {
        // A for step s+1 (LDS; s=15 redundant reload of step 0)
        const int sa = ((s + 1) & 15) * 32;
        const short8 a0n = *(const short8*)(arow0 + sa);
        const short8 a1n = *(const short8*)(arow1 + sa);
        // MFMA with current A and bbuf[s&1]
        acc[0][0] = __builtin_amdgcn_mfma_f32_16x16x32_bf16(a0c, bbuf[s & 1][0], acc[0][0], 0, 0, 0);
        acc[0][1] = __builtin_amdgcn_mfma_f32_16x16x32_bf16(a0c, bbuf[s & 1][1], acc[0][1], 0, 0, 0);
        acc[0][2] = __builtin_amdgcn_mfma_f32_16x16x32_bf16(a0c, bbuf[s & 1][2], acc[0][2], 0, 0, 0);
        acc[0][3] = __builtin_amdgcn_mfma_f32_16x16x32_bf16(a0c, bbuf[s & 1][3], acc[0][3], 0, 0, 0);
        acc[1][0] = __builtin_amdgcn_mfma_f32_16x16x32_bf16(a1c, bbuf[s & 1][0], acc[1][0], 0, 0, 0);
        acc[1][1] = __builtin_amdgcn_mfma_f32_16x16x32_bf16(a1c, bbuf[s & 1][1], acc[1][1], 0, 0, 0);
        acc[1][2] = __builtin_amdgcn_mfma_f32_16x16x32_bf16(a1c, bbuf[s & 1][2], acc[1][2], 0, 0, 0);
        acc[1][3] = __builtin_amdgcn_mfma_f32_16x16x32_bf16(a1c, bbuf[s & 1][3], acc[1][3], 0, 0, 0);
        // B prefetch for step s+2 into the slot just consumed (wraps, L2-hot)
        const int sn = ((s + 2) & 15) * 8192;
        bbuf[s & 1][0] = *(const short8*)(bp0 + sn);
        bbuf[s & 1][1] = *(const short8*)(bp1 + sn);
        bbuf[s & 1][2] = *(const short8*)(bp2 + sn);
        bbuf[s & 1][3] = *(const short8*)(bp3 + sn);
        a0c = a0n; a1c = a1n;
    }

    // conv as one extra K=32 MFMA step: A[t][k] = sw[t + k], B = CWT (permuted)
    {
        S8 ca0, ca1;
        #pragma unroll
        for (int j = 0; j < 4; ++j) {
            const int base0 = lm + lq * 8 + 2 * j;
            ca0.u[j] = cvt_pk(sw[base0],      sw[base0 + 1]);
            ca1.u[j] = cvt_pk(sw[base0 + 16], sw[base0 + 17]);
        }
        const short8 cb0 = *(const short8*)(cp0);
        const short8 cb1 = *(const short8*)(cp0 + 512);
        const short8 cb2 = *(const short8*)(cp0 + 1024);
        const short8 cb3 = *(const short8*)(cp0 + 1536);
        acc[0][0] = __builtin_amdgcn_mfma_f32_16x16x32_bf16(ca0.v, cb0, acc[0][0], 0, 0, 0);
        acc[0][1] = __builtin_amdgcn_mfma_f32_16x16x32_bf16(ca0.v, cb1, acc[0][1], 0, 0, 0);
        acc[0][2] = __builtin_amdgcn_mfma_f32_16x16x32_bf16(ca0.v, cb2, acc[0][2], 0, 0, 0);
        acc[0][3] = __builtin_amdgcn_mfma_f32_16x16x32_bf16(ca0.v, cb3, acc[0][3], 0, 0, 0);
        acc[1][0] = __builtin_amdgcn_mfma_f32_16x16x32_bf16(ca1.v, cb0, acc[1][0], 0, 0, 0);
        acc[1][1] = __builtin_amdgcn_mfma_f32_16x16x32_bf16(ca1.v, cb1, acc[1][1], 0, 0, 0);
        acc[1][2] = __builtin_amdgcn_mfma_f32_16x16x32_bf16(ca1.v, cb2, acc[1][2], 0, 0, 0);
        acc[1][3] = __builtin_amdgcn_mfma_f32_16x16x32_bf16(ca1.v, cb3, acc[1][3], 0, 0, 0);
    }

    // epilogue: zconst + tanh + v_a dot; reduce over the 16 n-lanes
    float zc[4], va[4];
    #pragma unroll
    for (int nbi = 0; nbi < 4; ++nbi) {
        const int col = ncol0 + nbi * 16;
        zc[nbi] = zconst[b * Un + col];
        va[nbi] = v_a[col];
    }
    #pragma unroll
    for (int mb = 0; mb < 2; ++mb) {
        #pragma unroll
        for (int r = 0; r < 4; ++r) {
            float ep = 0.f;
            #pragma unroll
            for (int nbi = 0; nbi < 4; ++nbi)
                ep += tanh_fast(acc[mb][nbi][r] + zc[nbi]) * va[nbi];
            ep += __shfl_xor(ep, 1, 64);
            ep += __shfl_xor(ep, 2, 64);
            ep += __shfl_xor(ep, 4, 64);
            ep += __shfl_xor(ep, 8, 64);
            if (lm == 0) ep_s[w][mb * 16 + lq * 4 + r] = ep;   // C/D: row = quad*4+reg
        }
    }
    __syncthreads();

    if (tid < 64) {
        float s = 0.f, st = 0.f;
        if (tid < TTILE) {
            const float energy = ep_s[0][tid] + ep_s[1][tid] + ep_s[2][tid] + ep_s[3][tid];
            s = __builtin_amdgcn_rcpf(1.0f + __expf(-energy));
            s_s[tid] = s;
            st = sw[15 + tid];
        }
        float ssum = s, stsum = st;
        #pragma unroll
        for (int off = 32; off >= 1; off >>= 1) {
            ssum  += __shfl_xor(ssum,  off, 64);
            stsum += __shfl_xor(stsum, off, 64);
        }
        if (tid == 0) {
            atomicAdd(&zSsum[b], ssum);
            atomicAdd(&zStsum[b], stsum);
        }
    }
    __syncthreads();

    // A/S weighted accumulation from the LDS bf16 tile; thread owns e = 2*tid, 2*tid+1
    const int e0 = tid << 1;
    float aA0 = 0.f, aA1 = 0.f, aS0 = 0.f, aS1 = 0.f;
    #pragma unroll 2
    for (int r4 = 0; r4 < TTILE / 4; ++r4) {
        const float4 sv4 = *(const float4*)&s_s[r4 * 4];
        const float4 st4 = *(const float4*)&sw[15 + r4 * 4];
        const float sv[4] = {sv4.x, sv4.y, sv4.z, sv4.w};
        const float st[4] = {st4.x, st4.y, st4.z, st4.w};
        #pragma unroll
        for (int j = 0; j < 4; ++j) {
            const int r = r4 * 4 + j;
            const uint_t mm = *(const uint_t*)&mem_s[r * LDK + e0];
            const float m0 = b2f(mm & 0xffffu);
            const float m1 = b2f(mm >> 16);
            aA0 += st[j] * m0; aA1 += st[j] * m1;
            aS0 += sv[j] * m0; aS1 += sv[j] * m1;
        }
    }
    atomicAdd(&zA[b * ENCn + e0],     aA0);
    atomicAdd(&zA[b * ENCn + e0 + 1], aA1);
    atomicAdd(&zS[b * ENCn + e0],     aS0);
    atomicAdd(&zS[b * ENCn + e0 + 1], aS1);
}

// ---------------- finalize ----------------
__global__ void k_final(const float* __restrict__ zA, const float* __restrict__ zS,
                        const float* __restrict__ zSsum, const float* __restrict__ zStsum,
                        const float* __restrict__ Wm, const float* __restrict__ bm,
                        float* __restrict__ out)
{
    const int b = blockIdx.x, e0 = blockIdx.y * 128, u = threadIdx.x;
    const float inv = 1.0f / zSsum[b];
    float a0 = 0.f, a1 = 0.f;
    #pragma unroll 4
    for (int e = e0; e < e0 + 128; e += 2) {
        const float c0 = zA[b * ENCn + e]     + zS[b * ENCn + e]     * inv;
        const float c1 = zA[b * ENCn + e + 1] + zS[b * ENCn + e + 1] * inv;
        a0 += c0 * Wm[(size_t)e * Un + u];
        a1 += c1 * Wm[(size_t)(e + 1) * Un + u];
    }
    float acc = a0 + a1;
    if (blockIdx.y == 0) acc += bm[u] * (zStsum[b] + 1.0f);
    atomicAdd(&out[b * Un + u], acc);
}

// ---------------- launch ----------------
extern "C" void kernel_launch(void* const* d_in, const int* in_sizes, int n_in,
                              void* d_out, int out_size, void* d_ws, size_t ws_size,
                              hipStream_t stream)
{
    const float* query  = (const float*)d_in[0];
    const float* state  = (const float*)d_in[1];
    const float* memory = (const float*)d_in[2];
    const float* Wq     = (const float*)d_in[3];
    const float* bq     = (const float*)d_in[4];
    const float* Wm     = (const float*)d_in[5];
    const float* bm     = (const float*)d_in[6];
    const float* Wl     = (const float*)d_in[7];
    const float* bl     = (const float*)d_in[8];
    const float* conv_w = (const float*)d_in[9];
    const float* conv_b = (const float*)d_in[10];
    const float* We     = (const float*)d_in[11];
    const float* be     = (const float*)d_in[12];
    const float* v_a    = (const float*)d_in[13];
    float* out = (float*)d_out;

    // workspace layout (float offsets)
    float* ws      = (float*)d_ws;
    float* zA      = ws;                   // 32768
    float* zS      = ws + 32768;           // 32768
    float* zSsum   = ws + 65536;           // 64
    float* zStsum  = ws + 65600;           // 64 -> zero ends 65664
    float* zconst  = ws + 65664;           // 16384 (direct-written, no memset needed)
    ushort_t* Bp    = (ushort_t*)(ws + 82048);   // 131072 ushorts (permuted WmWeT)
    ushort_t* CWT   = (ushort_t*)(ws + 147584);  // 8192 ushorts (permuted)

    hipMemsetAsync(ws, 0, 65664 * sizeof(float), stream);
    hipMemsetAsync(out, 0, (size_t)Bq * Un * sizeof(float), stream);

    hipLaunchKernelGGL(k_prep, dim3(516 + Bq), dim3(Un), 0, stream,
                       We, Wm, Wl, conv_w, bq, bm, bl, conv_b, query, Wq, be,
                       Bp, CWT, zconst);
    hipLaunchKernelGGL(attn_main, dim3(Bq * NCHUNK), dim3(256), 0, stream,
                       memory, state, Bp, CWT, zconst, v_a, zA, zS, zSsum, zStsum);
    hipLaunchKernelGGL(k_final, dim3(Bq, 4), dim3(Un), 0, stream,
                       zA, zS, zSsum, zStsum, Wm, bm, out);
}

// Round 7
// 505.683 us; speedup vs baseline: 1.4367x; 1.0217x over previous
//
#include <hip/hip_runtime.h>
#include <hip/hip_bf16.h>
#include <math.h>

// Problem constants
#define Bq 64
#define Tt 2048
#define TQn 2
#define HIDn 1024
#define ENCn 512
#define Un 256
#define FILTn 32
#define KKn 31

// Main-pass tiling
#define TTILE 32
#define NCHUNK (Tt / TTILE)     // 64
#define LDK 520                 // padded LDS row (bf16): 512+8, 16B-aligned rows

typedef short short8 __attribute__((ext_vector_type(8)));
typedef float f32x4  __attribute__((ext_vector_type(4)));
typedef float f32x4v __attribute__((ext_vector_type(4)));
typedef unsigned short ushort_t;
typedef unsigned int   uint_t;

union S8 { short8 v; uint_t u[4]; };

__device__ __forceinline__ ushort_t f2b(float f) {          // RNE scalar (prep only)
    union { float f; uint_t u; } x; x.f = f;
    uint_t r = x.u + 0x7fffu + ((x.u >> 16) & 1u);
    return (ushort_t)(r >> 16);
}
__device__ __forceinline__ uint_t cvt_pk(float lo, float hi) {  // HW v_cvt_pk_bf16_f32
    union { __hip_bfloat162 h; uint_t u; } x;
    x.h = __float22bfloat162_rn(make_float2(lo, hi));
    return x.u;
}
__device__ __forceinline__ float b2f(uint_t u16) {
    union { uint_t i; float f; } x; x.i = u16 << 16;
    return x.f;
}
__device__ __forceinline__ float tanh_fast(float x) {
    const float e = __expf(2.0f * x);
    return 1.0f - 2.0f * __builtin_amdgcn_rcpf(e + 1.0f);
}

// B-layout helper: element (v, k) of WmWe^T goes to the slot wave-load order expects:
// seg = (k>>5)*16 + (v>>6)*4 + ((v>>4)&3), lane = ((k>>3)&3)*16 + (v&15), j = k&7
// ushort idx = seg*512 + lane*8 + j   -> every wave B-load is one contiguous 1KB txn.
__device__ __forceinline__ int bp_idx(int v, int k) {
    const int seg = (k >> 5) * 16 + (v >> 6) * 4 + ((v >> 4) & 3);
    const int ln  = ((k >> 3) & 3) * 16 + (v & 15);
    return seg * 512 + ln * 8 + (k & 7);
}

// ---------------- k_prep: Bp (512 blks) + CWT (4 blks) + per-b g/zconst chain (64 blks) ----
__global__ void k_prep(const float* __restrict__ We, const float* __restrict__ Wm,
                       const float* __restrict__ Wl, const float* __restrict__ conv_w,
                       const float* __restrict__ bq, const float* __restrict__ bm,
                       const float* __restrict__ bl, const float* __restrict__ conv_b,
                       const float* __restrict__ query, const float* __restrict__ Wq,
                       const float* __restrict__ be,
                       ushort_t* __restrict__ Bp, ushort_t* __restrict__ CWT,
                       float* __restrict__ zconst)
{
    const int blk = blockIdx.x;
    __shared__ float wlwe[FILTn * 64];     // CWT branch
    __shared__ float g_lds[Un];            // gz branch
    if (blk < 512) {               // Bp slot for (v, k=e) = bf16(sum_u Wm[e,u] We[u,v])
        const int v = threadIdx.x;
        const int e = blk;
        float a0 = 0.f, a1 = 0.f, a2 = 0.f, a3 = 0.f;
        #pragma unroll 4
        for (int u = 0; u < Un; u += 4) {
            a0 += Wm[(size_t)e * Un + u + 0] * We[(u + 0) * Un + v];
            a1 += Wm[(size_t)e * Un + u + 1] * We[(u + 1) * Un + v];
            a2 += Wm[(size_t)e * Un + u + 2] * We[(u + 2) * Un + v];
            a3 += Wm[(size_t)e * Un + u + 3] * We[(u + 3) * Un + v];
        }
        Bp[bp_idx(v, e)] = f2b((a0 + a1) + (a2 + a3));
    } else if (blk < 516) {        // CWT (permuted, k<32) for a 64-wide v chunk
        const int vc = (blk - 512) * 64;
        for (int i = threadIdx.x; i < FILTn * 64; i += 256) {
            const int f = i >> 6, vv = i & 63;
            float a = 0.f;
            #pragma unroll 8
            for (int u = 0; u < Un; ++u) a += Wl[f * Un + u] * We[u * Un + vc + vv];
            wlwe[f * 64 + vv] = a;
        }
        __syncthreads();
        for (int i = threadIdx.x; i < 64 * 32; i += 256) {
            const int vv = i >> 5, k = i & 31;
            float a = 0.f;
            if (k < KKn) {
                #pragma unroll
                for (int f = 0; f < FILTn; ++f) a += conv_w[f * KKn + k] * wlwe[f * 64 + vv];
            }
            CWT[bp_idx(vc + vv, k)] = f2b(a);
        }
    } else {                       // per-b chain: cvec (reg) -> g (LDS) -> zconst (global)
        const int b = blk - 516;
        const int u = threadIdx.x;
        float cv = bq[u] + bm[u] + bl[u];
        #pragma unroll
        for (int f = 0; f < FILTn; ++f) cv += conv_b[f] * Wl[f * Un + u];
        const float* q = query + ((size_t)b * TQn + 1) * HIDn;
        float a0 = 0.f, a1 = 0.f, a2 = 0.f, a3 = 0.f;
        #pragma unroll 4
        for (int h = 0; h < HIDn; h += 4) {
            a0 += q[h + 0] * Wq[(size_t)(h + 0) * Un + u];
            a1 += q[h + 1] * Wq[(size_t)(h + 1) * Un + u];
            a2 += q[h + 2] * Wq[(size_t)(h + 2) * Un + u];
            a3 += q[h + 3] * Wq[(size_t)(h + 3) * Un + u];
        }
        g_lds[u] = cv + (a0 + a1) + (a2 + a3);
        __syncthreads();
        float z0 = 0.f, z1 = 0.f;
        #pragma unroll 4
        for (int uu = 0; uu < Un; uu += 2) {
            z0 += g_lds[uu]     * We[(size_t)uu * Un + u];
            z1 += g_lds[uu + 1] * We[(size_t)(uu + 1) * Un + u];
        }
        zconst[b * Un + u] = be[u] + z0 + z1;
    }
}

// ---------------- main fused MFMA pass (LDS tile, nt streaming, 3-deep B, no atomics) ----
// Block: (b, 32-row t-chunk), 256 thr = 4 waves; wave w owns v-cols w*64..w*64+63.
// Staging reads the memory tensor with NON-TEMPORAL loads (row-contiguous, full-line),
// issued before the B prefetch so the DRAM stream leads the VMEM queue. B table (Bp)
// is permuted (1KB wave txns) with a 3-deep rotating prefetch to cover L2 latency.
// zA/zS are written as per-block partials (coalesced stores) and reduced in k_final —
// no contended global atomics.
__global__ __launch_bounds__(256, 4) void attn_main(
    const float* __restrict__ memory, const float* __restrict__ state,
    const ushort_t* __restrict__ Bp, const ushort_t* __restrict__ CWT,
    const float* __restrict__ zconst, const float* __restrict__ v_a,
    float* __restrict__ pA, float* __restrict__ pS,
    float* __restrict__ zSsum, float* __restrict__ zStsum)
{
    const int blk = blockIdx.x;
    const int b  = blk >> 6;            // / NCHUNK
    const int c  = blk & (NCHUNK - 1);
    const int t0 = c * TTILE;
    const int tid = threadIdx.x;

    __shared__ __align__(16) ushort_t mem_s[TTILE * LDK];   // 33280 B
    __shared__ __align__(16) float sw_raw[80];
    __shared__ __align__(16) float ep_s[4][TTILE];
    __shared__ __align__(16) float s_s[TTILE];
    float* sw = sw_raw + 1;   // sw[i] = state[t0-15+i]

    // state window [t0-15, t0+47], zero-padded at sequence ends
    for (int i = tid; i < TTILE + 31; i += 256) {
        const int t = t0 - 15 + i;
        sw[i] = (t >= 0 && t < Tt) ? state[b * Tt + t] : 0.0f;
    }

    // stage 32x512 fp32 -> bf16 LDS tile (non-temporal, row-contiguous) — issued FIRST
    const f32x4v* memv4 = (const f32x4v*)(memory + ((size_t)b * Tt + t0) * ENCn);
    #pragma unroll
    for (int i = 0; i < 8; ++i) {
        const int idx = i * 256 + tid;          // 8-float chunk id, 0..2047
        const int row = idx >> 6;               // 64 chunks per row
        const int cw8 = (idx & 63) << 3;
        const f32x4v m0 = __builtin_nontemporal_load(memv4 + 2 * idx);
        const f32x4v m1 = __builtin_nontemporal_load(memv4 + 2 * idx + 1);
        S8 v;
        v.u[0] = cvt_pk(m0.x, m0.y); v.u[1] = cvt_pk(m0.z, m0.w);
        v.u[2] = cvt_pk(m1.x, m1.y); v.u[3] = cvt_pk(m1.z, m1.w);
        *(short8*)&mem_s[row * LDK + cw8] = v.v;
    }

    const int lane = tid & 63;
    const int w    = tid >> 6;
    const int lm   = lane & 15;
    const int lq   = lane >> 4;
    const int ncol0 = w * 64 + lm;

    // Permuted-B pointers: contiguous 1KB per wave-load. Per step s add s*8192 ushorts.
    const ushort_t* bp0 = Bp + (size_t)(w * 4) * 512 + lane * 8;
    const ushort_t* bp1 = bp0 + 512;
    const ushort_t* bp2 = bp0 + 1024;
    const ushort_t* bp3 = bp0 + 1536;
    const ushort_t* cp0 = CWT + (size_t)(w * 4) * 512 + lane * 8;

    // 3-deep B prefetch: steps 0,1,2 (slot = step % 3)
    short8 bbuf[3][4];
    #pragma unroll
    for (int d = 0; d < 3; ++d) {
        bbuf[d][0] = *(const short8*)(bp0 + d * 8192);
        bbuf[d][1] = *(const short8*)(bp1 + d * 8192);
        bbuf[d][2] = *(const short8*)(bp2 + d * 8192);
        bbuf[d][3] = *(const short8*)(bp3 + d * 8192);
    }

    f32x4 acc[2][4] = {};

    __syncthreads();

    const ushort_t* arow0 = &mem_s[(lm) * LDK + lq * 8];
    const ushort_t* arow1 = &mem_s[(16 + lm) * LDK + lq * 8];

    // A pipeline: load step 0
    short8 a0c = *(const short8*)(arow0);
    short8 a1c = *(const short8*)(arow1);

    #pragma unroll
    for (int s = 0; s < 16; ++s) {
        const int sl = s % 3;
        // A for step s+1 (LDS; s=15 redundant reload of step 0)
        const int sa = ((s + 1) & 15) * 32;
        const short8 a0n = *(const short8*)(arow0 + sa);
        const short8 a1n = *(const short8*)(arow1 + sa);
        // MFMA with current A and bbuf[sl]
        acc[0][0] = __builtin_amdgcn_mfma_f32_16x16x32_bf16(a0c, bbuf[sl][0], acc[0][0], 0, 0, 0);
        acc[0][1] = __builtin_amdgcn_mfma_f32_16x16x32_bf16(a0c, bbuf[sl][1], acc[0][1], 0, 0, 0);
        acc[0][2] = __builtin_amdgcn_mfma_f32_16x16x32_bf16(a0c, bbuf[sl][2], acc[0][2], 0, 0, 0);
        acc[0][3] = __builtin_amdgcn_mfma_f32_16x16x32_bf16(a0c, bbuf[sl][3], acc[0][3], 0, 0, 0);
        acc[1][0] = __builtin_amdgcn_mfma_f32_16x16x32_bf16(a1c, bbuf[sl][0], acc[1][0], 0, 0, 0);
        acc[1][1] = __builtin_amdgcn_mfma_f32_16x16x32_bf16(a1c, bbuf[sl][1], acc[1][1], 0, 0, 0);
        acc[1][2] = __builtin_amdgcn_mfma_f32_16x16x32_bf16(a1c, bbuf[sl][2], acc[1][2], 0, 0, 0);
        acc[1][3] = __builtin_amdgcn_mfma_f32_16x16x32_bf16(a1c, bbuf[sl][3], acc[1][3], 0, 0, 0);
        // B prefetch for step s+3 into the slot just consumed (wraps at end, harmless)
        const int sn = ((s + 3) & 15) * 8192;
        bbuf[sl][0] = *(const short8*)(bp0 + sn);
        bbuf[sl][1] = *(const short8*)(bp1 + sn);
        bbuf[sl][2] = *(const short8*)(bp2 + sn);
        bbuf[sl][3] = *(const short8*)(bp3 + sn);
        a0c = a0n; a1c = a1n;
    }

    // conv as one extra K=32 MFMA step: A[t][k] = sw[t + k], B = CWT (permuted)
    {
        S8 ca0, ca1;
        #pragma unroll
        for (int j = 0; j < 4; ++j) {
            const int base0 = lm + lq * 8 + 2 * j;
            ca0.u[j] = cvt_pk(sw[base0],      sw[base0 + 1]);
            ca1.u[j] = cvt_pk(sw[base0 + 16], sw[base0 + 17]);
        }
        const short8 cb0 = *(const short8*)(cp0);
        const short8 cb1 = *(const short8*)(cp0 + 512);
        const short8 cb2 = *(const short8*)(cp0 + 1024);
        const short8 cb3 = *(const short8*)(cp0 + 1536);
        acc[0][0] = __builtin_amdgcn_mfma_f32_16x16x32_bf16(ca0.v, cb0, acc[0][0], 0, 0, 0);
        acc[0][1] = __builtin_amdgcn_mfma_f32_16x16x32_bf16(ca0.v, cb1, acc[0][1], 0, 0, 0);
        acc[0][2] = __builtin_amdgcn_mfma_f32_16x16x32_bf16(ca0.v, cb2, acc[0][2], 0, 0, 0);
        acc[0][3] = __builtin_amdgcn_mfma_f32_16x16x32_bf16(ca0.v, cb3, acc[0][3], 0, 0, 0);
        acc[1][0] = __builtin_amdgcn_mfma_f32_16x16x32_bf16(ca1.v, cb0, acc[1][0], 0, 0, 0);
        acc[1][1] = __builtin_amdgcn_mfma_f32_16x16x32_bf16(ca1.v, cb1, acc[1][1], 0, 0, 0);
        acc[1][2] = __builtin_amdgcn_mfma_f32_16x16x32_bf16(ca1.v, cb2, acc[1][2], 0, 0, 0);
        acc[1][3] = __builtin_amdgcn_mfma_f32_16x16x32_bf16(ca1.v, cb3, acc[1][3], 0, 0, 0);
    }

    // epilogue: zconst + tanh + v_a dot; reduce over the 16 n-lanes
    float zc[4], va[4];
    #pragma unroll
    for (int nbi = 0; nbi < 4; ++nbi) {
        const int col = ncol0 + nbi * 16;
        zc[nbi] = zconst[b * Un + col];
        va[nbi] = v_a[col];
    }
    #pragma unroll
    for (int mb = 0; mb < 2; ++mb) {
        #pragma unroll
        for (int r = 0; r < 4; ++r) {
            float ep = 0.f;
            #pragma unroll
            for (int nbi = 0; nbi < 4; ++nbi)
                ep += tanh_fast(acc[mb][nbi][r] + zc[nbi]) * va[nbi];
            ep += __shfl_xor(ep, 1, 64);
            ep += __shfl_xor(ep, 2, 64);
            ep += __shfl_xor(ep, 4, 64);
            ep += __shfl_xor(ep, 8, 64);
            if (lm == 0) ep_s[w][mb * 16 + lq * 4 + r] = ep;   // C/D: row = quad*4+reg
        }
    }
    __syncthreads();

    if (tid < 64) {
        float s = 0.f, st = 0.f;
        if (tid < TTILE) {
            const float energy = ep_s[0][tid] + ep_s[1][tid] + ep_s[2][tid] + ep_s[3][tid];
            s = __builtin_amdgcn_rcpf(1.0f + __expf(-energy));
            s_s[tid] = s;
            st = sw[15 + tid];
        }
        float ssum = s, stsum = st;
        #pragma unroll
        for (int off = 32; off >= 1; off >>= 1) {
            ssum  += __shfl_xor(ssum,  off, 64);
            stsum += __shfl_xor(stsum, off, 64);
        }
        if (tid == 0) {
            atomicAdd(&zSsum[b], ssum);
            atomicAdd(&zStsum[b], stsum);
        }
    }
    __syncthreads();

    // A/S weighted accumulation from the LDS bf16 tile; thread owns e = 2*tid, 2*tid+1.
    // Partials stored per-block (coalesced float2), reduced in k_final — no atomics.
    const int e0 = tid << 1;
    float aA0 = 0.f, aA1 = 0.f, aS0 = 0.f, aS1 = 0.f;
    #pragma unroll 2
    for (int r4 = 0; r4 < TTILE / 4; ++r4) {
        const float4 sv4 = *(const float4*)&s_s[r4 * 4];
        const float4 st4 = *(const float4*)&sw[15 + r4 * 4];
        const float sv[4] = {sv4.x, sv4.y, sv4.z, sv4.w};
        const float st[4] = {st4.x, st4.y, st4.z, st4.w};
        #pragma unroll
        for (int j = 0; j < 4; ++j) {
            const int r = r4 * 4 + j;
            const uint_t mm = *(const uint_t*)&mem_s[r * LDK + e0];
            const float m0 = b2f(mm & 0xffffu);
            const float m1 = b2f(mm >> 16);
            aA0 += st[j] * m0; aA1 += st[j] * m1;
            aS0 += sv[j] * m0; aS1 += sv[j] * m1;
        }
    }
    *(float2*)(pA + (size_t)blk * ENCn + e0) = make_float2(aA0, aA1);
    *(float2*)(pS + (size_t)blk * ENCn + e0) = make_float2(aS0, aS1);
}

// ---------------- finalize: reduce per-block partials (LDS) + Wm projection -------------
__global__ void k_final(const float* __restrict__ pA, const float* __restrict__ pS,
                        const float* __restrict__ zSsum, const float* __restrict__ zStsum,
                        const float* __restrict__ Wm, const float* __restrict__ bm,
                        float* __restrict__ out)
{
    const int b = blockIdx.x, e0 = blockIdx.y * 128, u = threadIdx.x;
    __shared__ float redA[256], redS[256];
    __shared__ float zAr[128], zSr[128];
    {
        const int el = u & 127;               // e-local
        const int ch = (u >> 7) * 32;         // c half: [ch, ch+32)
        const float* bA = pA + ((size_t)b * NCHUNK + ch) * ENCn + e0 + el;
        const float* bS = pS + ((size_t)b * NCHUNK + ch) * ENCn + e0 + el;
        float aA = 0.f, aS = 0.f;
        #pragma unroll 8
        for (int cc = 0; cc < 32; ++cc) {
            aA += bA[(size_t)cc * ENCn];
            aS += bS[(size_t)cc * ENCn];
        }
        redA[u] = aA; redS[u] = aS;
    }
    __syncthreads();
    if (u < 128) {
        zAr[u] = redA[u] + redA[u + 128];
        zSr[u] = redS[u] + redS[u + 128];
    }
    __syncthreads();

    const float inv = 1.0f / zSsum[b];
    float a0 = 0.f, a1 = 0.f;
    #pragma unroll 4
    for (int i = 0; i < 128; i += 2) {
        const float c0 = zAr[i]     + zSr[i]     * inv;
        const float c1 = zAr[i + 1] + zSr[i + 1] * inv;
        a0 += c0 * Wm[(size_t)(e0 + i) * Un + u];
        a1 += c1 * Wm[(size_t)(e0 + i + 1) * Un + u];
    }
    float acc = a0 + a1;
    if (blockIdx.y == 0) acc += bm[u] * (zStsum[b] + 1.0f);
    atomicAdd(&out[b * Un + u], acc);
}

// ---------------- launch ----------------
extern "C" void kernel_launch(void* const* d_in, const int* in_sizes, int n_in,
                              void* d_out, int out_size, void* d_ws, size_t ws_size,
                              hipStream_t stream)
{
    const float* query  = (const float*)d_in[0];
    const float* state  = (const float*)d_in[1];
    const float* memory = (const float*)d_in[2];
    const float* Wq     = (const float*)d_in[3];
    const float* bq     = (const float*)d_in[4];
    const float* Wm     = (const float*)d_in[5];
    const float* bm     = (const float*)d_in[6];
    const float* Wl     = (const float*)d_in[7];
    const float* bl     = (const float*)d_in[8];
    const float* conv_w = (const float*)d_in[9];
    const float* conv_b = (const float*)d_in[10];
    const float* We     = (const float*)d_in[11];
    const float* be     = (const float*)d_in[12];
    const float* v_a    = (const float*)d_in[13];
    float* out = (float*)d_out;

    // workspace layout (float offsets)
    float* ws      = (float*)d_ws;
    float* zSsum   = ws;                        // 64
    float* zStsum  = ws + 64;                   // 64 -> zero ends 128
    float* zconst  = ws + 128;                  // 16384 (direct-written)
    float* pA      = ws + 16512;                // 4096*512 = 2,097,152
    float* pS      = ws + 2113664;              // 2,097,152
    ushort_t* Bp    = (ushort_t*)(ws + 4210816);   // 131072 ushorts (permuted WmWeT)
    ushort_t* CWT   = (ushort_t*)(ws + 4276352);   // 8192 ushorts (permuted)

    hipMemsetAsync(ws, 0, 128 * sizeof(float), stream);
    hipMemsetAsync(out, 0, (size_t)Bq * Un * sizeof(float), stream);

    hipLaunchKernelGGL(k_prep, dim3(516 + Bq), dim3(Un), 0, stream,
                       We, Wm, Wl, conv_w, bq, bm, bl, conv_b, query, Wq, be,
                       Bp, CWT, zconst);
    hipLaunchKernelGGL(attn_main, dim3(Bq * NCHUNK), dim3(256), 0, stream,
                       memory, state, Bp, CWT, zconst, v_a, pA, pS, zSsum, zStsum);
    hipLaunchKernelGGL(k_final, dim3(Bq, 4), dim3(Un), 0, stream,
                       pA, pS, zSsum, zStsum, Wm, bm, out);
}